// Round 7
// baseline (793.512 us; speedup 1.0000x reference)
//
#include <hip/hip_runtime.h>
#include <math.h>

#define N 2048
#define D 256
#define H 8
#define DK 32
#define L 4
#define DFF 1024
#define NEDGE 5
#define JC 8  // attention j-chunks (flash-decode split)

typedef short short8 __attribute__((ext_vector_type(8)));
typedef float floatx4 __attribute__((ext_vector_type(4)));

// Q pre-scale: 1/sqrt(DK) * log2(e)  (attention uses raw v_exp_f32 = exp2)
#define QSCALE 0.25503485657f
#define LOG2E 1.4426950408889634f

#define MFMA(a, b, c) __builtin_amdgcn_mfma_f32_16x16x32_bf16(a, b, c, 0, 0, 0)

#define AB_STR 280
#define PB_STR 72

__device__ __forceinline__ unsigned short f2bf(float f) {
  unsigned int u = __float_as_uint(f);
  u += 0x7fffu + ((u >> 16) & 1u);
  return (unsigned short)(u >> 16);
}

__device__ __forceinline__ float exp2_hw(float x) {
  float r;
  asm("v_exp_f32 %0, %1" : "=v"(r) : "v"(x));
  return r;
}

__device__ __forceinline__ unsigned int cvt_pk_bf16(float lo, float hi) {
  unsigned int r;
  asm("v_cvt_pk_bf16_f32 %0, %1, %2" : "=v"(r) : "v"(lo), "v"(hi));
  return r;
}

__device__ __forceinline__ void async16(unsigned short* lds, const unsigned short* g) {
  __builtin_amdgcn_global_load_lds(
      (const __attribute__((address_space(1))) unsigned int*)g,
      (__attribute__((address_space(3))) unsigned int*)lds, 16, 0, 0);
}

// ---- setup: e8 pack + weight transposes + WrT fp32 + counter zero ---------
// blocks [0,4096): e8 pack; [4096,5120): Wq/Wk/Wv/Wo; [5120,6144): W1;
// [6144,7168): W2; [7168,7296): Wr fp32 transpose; 7296: zero cnt.
__global__ __launch_bounds__(256) void k_setup(
    const int* __restrict__ eidx, unsigned int* __restrict__ e8,
    const float* __restrict__ Wq, const float* __restrict__ Wk,
    const float* __restrict__ Wv, const float* __restrict__ Wo,
    const float* __restrict__ W1, const float* __restrict__ W2,
    const float* __restrict__ Wr,
    unsigned short* __restrict__ wqkvb, unsigned short* __restrict__ wob,
    unsigned short* __restrict__ w1b, unsigned short* __restrict__ w2b,
    float* __restrict__ WrT, int* __restrict__ cnt) {
  __shared__ float t[32][33];
  const int blk = blockIdx.x;
  const int tid = threadIdx.x;
  if (blk < 4096) {
    int i = blk * 256 + tid;
    int4 v = ((const int4*)eidx)[i];
    e8[i] = (unsigned int)(v.x & 0xff) | ((unsigned int)(v.y & 0xff) << 8) |
            ((unsigned int)(v.z & 0xff) << 16) | ((unsigned int)(v.w & 0xff) << 24);
    return;
  }
  if (blk == 7296) {
    if (tid < 4 * 32) cnt[tid] = 0;
    return;
  }
  const int tx = tid & 31, ty = tid >> 5;
  if (blk >= 7168) {  // Wr (512,256) fp32 -> WrT (256,512) fp32
    int b5 = blk - 7168, bx = b5 & 7, by = b5 >> 3;
#pragma unroll
    for (int i = 0; i < 32; i += 8)
      t[ty + i][tx] = Wr[(size_t)(by * 32 + ty + i) * D + bx * 32 + tx];
    __syncthreads();
#pragma unroll
    for (int i = 0; i < 32; i += 8)
      WrT[(size_t)(bx * 32 + ty + i) * 512 + by * 32 + tx] = t[tx][ty + i];
    return;
  }
  const float* s;
  unsigned short* d;
  int rowOff, K_, N_, bx, by;
  if (blk < 5120) {
    int b2 = blk - 4096, z = b2 >> 6, rem = b2 & 63;
    int which = z >> 2, l = z & 3;
    s = (which == 0 ? Wq : which == 1 ? Wk : which == 2 ? Wv : Wo) + (size_t)l * D * D;
    if (which < 3) { d = wqkvb + (size_t)l * 768 * D; rowOff = which * 256; }
    else           { d = wob + (size_t)l * D * D;     rowOff = 0; }
    K_ = D; N_ = D; bx = rem & 7; by = rem >> 3;
  } else if (blk < 6144) {
    int b3 = blk - 5120, l = b3 >> 8, rem = b3 & 255;
    s = W1 + (size_t)l * D * DFF; d = w1b + (size_t)l * DFF * D; rowOff = 0;
    K_ = D; N_ = DFF; bx = rem & 31; by = rem >> 5;
  } else {
    int b4 = blk - 6144, l = b4 >> 8, rem = b4 & 255;
    s = W2 + (size_t)l * DFF * D; d = w2b + (size_t)l * D * DFF; rowOff = 0;
    K_ = DFF; N_ = D; bx = rem & 7; by = rem >> 3;
  }
  int n0 = bx * 32, k0 = by * 32;
#pragma unroll
  for (int i = 0; i < 32; i += 8) t[ty + i][tx] = s[(size_t)(k0 + ty + i) * N_ + n0 + tx];
  __syncthreads();
#pragma unroll
  for (int i = 0; i < 32; i += 8)
    d[(size_t)(rowOff + n0 + ty + i) * K_ + k0 + tx] = f2bf(t[tx][ty + i]);
}

// ---- qkv tail for 8-wave/16-row blocks (embed kernel only) ----------------
__device__ __forceinline__ void qkv_from_Ab8(
    const unsigned short* Ab, const unsigned short* __restrict__ wqkv,
    unsigned short* __restrict__ qb, unsigned short* __restrict__ kb,
    unsigned short* __restrict__ vtb, int r0, int w, int quad, int c16) {
  short8 af[8];
#pragma unroll
  for (int k = 0; k < 8; ++k)
    af[k] = *(const short8*)&Ab[c16 * AB_STR + k * 32 + quad * 8];
#pragma unroll
  for (int tp = 0; tp < 3; ++tp) {
    const int cb0 = (w * 6 + tp * 2) * 16 + c16;
    const int cb1 = cb0 + 16;
    const unsigned short* B0 = wqkv + (size_t)cb0 * D + quad * 8;
    const unsigned short* B1 = wqkv + (size_t)cb1 * D + quad * 8;
    floatx4 a0 = {0.f, 0.f, 0.f, 0.f}, a1 = {0.f, 0.f, 0.f, 0.f};
#pragma unroll
    for (int k = 0; k < 8; ++k) {
      a0 = MFMA(af[k], *(const short8*)(B0 + k * 32), a0);
      a1 = MFMA(af[k], *(const short8*)(B1 + k * 32), a1);
    }
#pragma unroll
    for (int e = 0; e < 4; ++e) {
      const int grow = r0 + quad * 4 + e;
#pragma unroll
      for (int half = 0; half < 2; ++half) {
        int gc = half ? cb1 : cb0;
        float v = half ? a1[e] : a0[e];
        if (gc < 256)      qb[(size_t)grow * D + gc] = f2bf(v * QSCALE);
        else if (gc < 512) kb[(size_t)grow * D + (gc - 256)] = f2bf(v);
        else               vtb[(size_t)(gc - 512) * N + grow] = f2bf(v);
      }
    }
  }
}

// ---- embed + layer-0 QKV --------------------------------------------------
__global__ __launch_bounds__(512) void k_embed_qkv(
    const int* __restrict__ nt, const float* __restrict__ emb,
    const unsigned short* __restrict__ wqkv0, float* __restrict__ x,
    unsigned short* __restrict__ qb, unsigned short* __restrict__ kb,
    unsigned short* __restrict__ vtb) {
  __shared__ __align__(16) unsigned short Ab[16 * AB_STR];
  const int tid = threadIdx.x;
  const int w = tid >> 6, lane = tid & 63, quad = lane >> 4, c16 = lane & 15;
  const int r0 = blockIdx.x * 16;
  {
    const int r = tid >> 5, cb = (tid & 31) * 8;
    const int ty = nt[r0 + r];
    float4 a = *(const float4*)&emb[(size_t)ty * D + cb];
    float4 b = *(const float4*)&emb[(size_t)ty * D + cb + 4];
    *(float4*)&x[(size_t)(r0 + r) * D + cb] = a;
    *(float4*)&x[(size_t)(r0 + r) * D + cb + 4] = b;
    Ab[r * AB_STR + cb + 0] = f2bf(a.x); Ab[r * AB_STR + cb + 1] = f2bf(a.y);
    Ab[r * AB_STR + cb + 2] = f2bf(a.z); Ab[r * AB_STR + cb + 3] = f2bf(a.w);
    Ab[r * AB_STR + cb + 4] = f2bf(b.x); Ab[r * AB_STR + cb + 5] = f2bf(b.y);
    Ab[r * AB_STR + cb + 6] = f2bf(b.z); Ab[r * AB_STR + cb + 7] = f2bf(b.w);
  }
  __syncthreads();
  qkv_from_Ab8(Ab, wqkv0, qb, kb, vtb, r0, w, quad, c16);
}

// ---- MFMA flash attention: QBLK=32, JC=8, m=0, contiguous-P ---------------
__global__ __launch_bounds__(512) void k_attn(const unsigned short* __restrict__ qb,
                                              const unsigned short* __restrict__ kb,
                                              const unsigned short* __restrict__ vt,
                                              const unsigned int* __restrict__ e8,
                                              const float* __restrict__ eb,
                                              float* __restrict__ Opart,
                                              float* __restrict__ lpart) {
  __shared__ __align__(16) unsigned short Pb[H][32 * PB_STR];
  __shared__ float ebh[H][NEDGE];
  __shared__ unsigned int e8s[32][65];
  const int tid = threadIdx.x;
  const int h = tid >> 6;
  const int lane = tid & 63;
  const int quad = lane >> 4;
  const int c16 = lane & 15;
  const int r0 = blockIdx.x * 32;
  const int jc = blockIdx.y;

  if (tid < NEDGE * H) ebh[tid % H][tid / H] = eb[tid] * LOG2E;
  for (int i = tid; i < 32 * 64; i += 512) {
    int r = i >> 6, ww = i & 63;
    e8s[r][ww] = e8[(size_t)(r0 + r) * (N / 4) + jc * 64 + ww];
  }
  __syncthreads();

  short8 aqA = *(const short8*)&qb[(size_t)(r0 + c16) * D + h * DK + quad * 8];
  short8 aqB = *(const short8*)&qb[(size_t)(r0 + 16 + c16) * D + h * DK + quad * 8];

  float lrowA[4] = {0.f, 0.f, 0.f, 0.f};
  float lrowB[4] = {0.f, 0.f, 0.f, 0.f};
  floatx4 O0A = {0.f, 0.f, 0.f, 0.f}, O1A = {0.f, 0.f, 0.f, 0.f};
  floatx4 O0B = {0.f, 0.f, 0.f, 0.f}, O1B = {0.f, 0.f, 0.f, 0.f};

  for (int g = 0; g < (N / JC) / 64; ++g) {
    const int j0 = jc * (N / JC) + g * 64;
    short8 bk[4];
#pragma unroll
    for (int t = 0; t < 4; ++t)
      bk[t] = *(const short8*)&kb[(size_t)(j0 + c16 * 4 + t) * D + h * DK + quad * 8];
    {
      unsigned int wrd[4];
#pragma unroll
      for (int e = 0; e < 4; ++e) wrd[e] = e8s[quad * 4 + e][g * 16 + c16];
      floatx4 Sc[4];
#pragma unroll
      for (int t = 0; t < 4; ++t) {
        floatx4 cbv;
#pragma unroll
        for (int e = 0; e < 4; ++e) cbv[e] = ebh[h][(wrd[e] >> (8 * t)) & 0xff];
        Sc[t] = MFMA(aqA, bk[t], cbv);
      }
      float p[4][4];
#pragma unroll
      for (int e = 0; e < 4; ++e) {
#pragma unroll
        for (int t = 0; t < 4; ++t) p[t][e] = exp2_hw(Sc[t][e]);
        lrowA[e] += (p[0][e] + p[1][e]) + (p[2][e] + p[3][e]);
      }
#pragma unroll
      for (int e = 0; e < 4; ++e) {
        uint2 u;
        u.x = cvt_pk_bf16(p[0][e], p[1][e]);
        u.y = cvt_pk_bf16(p[2][e], p[3][e]);
        *(uint2*)&Pb[h][(quad * 4 + e) * PB_STR + c16 * 4] = u;
      }
    }
    {
      unsigned int wrd[4];
#pragma unroll
      for (int e = 0; e < 4; ++e) wrd[e] = e8s[16 + quad * 4 + e][g * 16 + c16];
      floatx4 Sc[4];
#pragma unroll
      for (int t = 0; t < 4; ++t) {
        floatx4 cbv;
#pragma unroll
        for (int e = 0; e < 4; ++e) cbv[e] = ebh[h][(wrd[e] >> (8 * t)) & 0xff];
        Sc[t] = MFMA(aqB, bk[t], cbv);
      }
      float p[4][4];
#pragma unroll
      for (int e = 0; e < 4; ++e) {
#pragma unroll
        for (int t = 0; t < 4; ++t) p[t][e] = exp2_hw(Sc[t][e]);
        lrowB[e] += (p[0][e] + p[1][e]) + (p[2][e] + p[3][e]);
      }
#pragma unroll
      for (int e = 0; e < 4; ++e) {
        uint2 u;
        u.x = cvt_pk_bf16(p[0][e], p[1][e]);
        u.y = cvt_pk_bf16(p[2][e], p[3][e]);
        *(uint2*)&Pb[h][(16 + quad * 4 + e) * PB_STR + c16 * 4] = u;
      }
    }
    asm volatile("" ::: "memory");
#pragma unroll
    for (int jj = 0; jj < 2; ++jj) {
      short8 apA = *(const short8*)&Pb[h][c16 * PB_STR + jj * 32 + quad * 8];
      short8 apB = *(const short8*)&Pb[h][(16 + c16) * PB_STR + jj * 32 + quad * 8];
      short8 bv0 = *(const short8*)&vt[(size_t)(h * DK + c16) * N + j0 + jj * 32 + quad * 8];
      short8 bv1 = *(const short8*)&vt[(size_t)(h * DK + 16 + c16) * N + j0 + jj * 32 + quad * 8];
      O0A = MFMA(apA, bv0, O0A); O1A = MFMA(apA, bv1, O1A);
      O0B = MFMA(apB, bv0, O0B); O1B = MFMA(apB, bv1, O1B);
    }
    asm volatile("" ::: "memory");
  }

#pragma unroll
  for (int e = 0; e < 4; ++e) {
    float va = lrowA[e], vb = lrowB[e];
    va += __shfl_xor(va, 1); va += __shfl_xor(va, 2);
    va += __shfl_xor(va, 4); va += __shfl_xor(va, 8);
    vb += __shfl_xor(vb, 1); vb += __shfl_xor(vb, 2);
    vb += __shfl_xor(vb, 4); vb += __shfl_xor(vb, 8);
    lrowA[e] = va; lrowB[e] = vb;
  }
#pragma unroll
  for (int e = 0; e < 4; ++e) {
    int rowA = r0 + quad * 4 + e, rowB = rowA + 16;
    size_t obA = ((size_t)jc * N + rowA) * D + h * DK;
    size_t obB = ((size_t)jc * N + rowB) * D + h * DK;
    Opart[obA + c16] = O0A[e];
    Opart[obA + 16 + c16] = O1A[e];
    Opart[obB + c16] = O0B[e];
    Opart[obB + 16 + c16] = O1B[e];
    if (c16 == 0) {
      lpart[((size_t)jc * N + rowA) * H + h] = lrowA[e];
      lpart[((size_t)jc * N + rowB) * H + h] = lrowB[e];
    }
  }
}

// ---- fused: attn-combine -> out-proj GEMM -> +bo +res -> LN1 -> x, xb -----
__global__ __launch_bounds__(256) void k_opln1(
    const float* __restrict__ Opart, const float* __restrict__ lpart,
    const unsigned short* __restrict__ wo, const float* __restrict__ bo,
    const float* __restrict__ g1, const float* __restrict__ be1,
    float* __restrict__ x, unsigned short* __restrict__ xb) {
  __shared__ __align__(16) unsigned short Ab[16 * AB_STR];
  __shared__ __align__(16) float Xr[16][260];
  __shared__ float linv[16][8];
  __shared__ float red1[4][16], red2[4][16], mu[16], rsg[16];
  const int tid = threadIdx.x;
  const int w = tid >> 6, lane = tid & 63, quad = lane >> 4, c16 = lane & 15;
  const int r0 = blockIdx.x * 16;

  if (tid < 128) {
    int r = tid >> 3, hh = tid & 7;
    float ls = 0.f;
#pragma unroll
    for (int c = 0; c < JC; ++c) ls += lpart[((size_t)c * N + r0 + r) * H + hh];
    linv[r][hh] = 1.f / ls;
  }
  for (int i = tid; i < 16 * 64; i += 256) {
    int r = i >> 6, c4 = (i & 63) * 4;
    *(float4*)&Xr[r][c4] = *(const float4*)&x[(size_t)(r0 + r) * D + c4];
  }
  __syncthreads();
  {
    const int r = tid >> 4, c0 = (tid & 15) * 16;
    float o[16];
#pragma unroll
    for (int j = 0; j < 16; ++j) o[j] = 0.f;
#pragma unroll
    for (int c = 0; c < JC; ++c) {
      const float* p = &Opart[((size_t)c * N + r0 + r) * D + c0];
#pragma unroll
      for (int j4 = 0; j4 < 4; ++j4) {
        float4 pv = *(const float4*)(p + j4 * 4);
        o[j4 * 4 + 0] += pv.x; o[j4 * 4 + 1] += pv.y;
        o[j4 * 4 + 2] += pv.z; o[j4 * 4 + 3] += pv.w;
      }
    }
    const float iv = linv[r][c0 >> 5];
#pragma unroll
    for (int j = 0; j < 16; j += 2)
      *(unsigned int*)&Ab[r * AB_STR + c0 + j] = cvt_pk_bf16(o[j] * iv, o[j + 1] * iv);
  }
  __syncthreads();

  short8 af[8];
#pragma unroll
  for (int k = 0; k < 8; ++k)
    af[k] = *(const short8*)&Ab[c16 * AB_STR + k * 32 + quad * 8];
  floatx4 acc[4] = {{0.f, 0.f, 0.f, 0.f}, {0.f, 0.f, 0.f, 0.f},
                    {0.f, 0.f, 0.f, 0.f}, {0.f, 0.f, 0.f, 0.f}};
#pragma unroll
  for (int ntt = 0; ntt < 4; ++ntt) {
    const int col = w * 64 + ntt * 16 + c16;
    const unsigned short* B = wo + (size_t)col * D + quad * 8;
#pragma unroll
    for (int k = 0; k < 8; ++k) acc[ntt] = MFMA(af[k], *(const short8*)(B + k * 32), acc[ntt]);
  }
  float v[4][4];
#pragma unroll
  for (int e = 0; e < 4; ++e) {
    const int row = quad * 4 + e;
    float s = 0.f, q = 0.f;
#pragma unroll
    for (int ntt = 0; ntt < 4; ++ntt) {
      const int col = w * 64 + ntt * 16 + c16;
      float vv = acc[ntt][e] + bo[col] + Xr[row][col];
      v[ntt][e] = vv;
      s += vv; q += vv * vv;
    }
    s += __shfl_xor(s, 1); s += __shfl_xor(s, 2);
    s += __shfl_xor(s, 4); s += __shfl_xor(s, 8);
    q += __shfl_xor(q, 1); q += __shfl_xor(q, 2);
    q += __shfl_xor(q, 4); q += __shfl_xor(q, 8);
    if (c16 == 0) { red1[w][row] = s; red2[w][row] = q; }
  }
  __syncthreads();
  if (tid < 16) {
    float m = red1[0][tid] + red1[1][tid] + red1[2][tid] + red1[3][tid];
    float q = red2[0][tid] + red2[1][tid] + red2[2][tid] + red2[3][tid];
    m *= (1.f / 256.f);
    q = q * (1.f / 256.f) - m * m;
    mu[tid] = m;
    rsg[tid] = rsqrtf(q + 1e-5f);
  }
  __syncthreads();
#pragma unroll
  for (int e = 0; e < 4; ++e) {
    const int row = quad * 4 + e;
#pragma unroll
    for (int ntt = 0; ntt < 4; ++ntt) {
      const int col = w * 64 + ntt * 16 + c16;
      float o = (v[ntt][e] - mu[row]) * rsg[row] * g1[col] + be1[col];
      x[(size_t)(r0 + row) * D + col] = o;
      xb[(size_t)(r0 + row) * D + col] = f2bf(o);
    }
  }
}

// ---- bf16 MFMA GEMM (FFN1): C = A(M,K) @ Bt(Nn,K)^T +bias +gelu -> bf16 ---
__global__ __launch_bounds__(256) void k_mm(const unsigned short* __restrict__ A,
                                            const unsigned short* __restrict__ Bt,
                                            int Nn, int Kfull, int Klen,
                                            const float* __restrict__ bias,
                                            int gelu,
                                            float* __restrict__ outf,
                                            unsigned short* __restrict__ outb) {
  __shared__ unsigned short As[64 * 32];
  __shared__ unsigned short Bs[64 * 32];
  int tid = threadIdx.x;
  int w = tid >> 6, lane = tid & 63, quad = lane >> 4, c16 = lane & 15;
  int bm = blockIdx.y * 64, bn = blockIdx.x * 64;
  int z = blockIdx.z;
  int kBase = z * Klen;
  int srow = w * 16 + (lane >> 2);
  int schk = (lane & 3) * 8;
  const unsigned short* gA = A + (size_t)(bm + srow) * Kfull + kBase + schk;
  const unsigned short* gB = Bt + (size_t)(bn + srow) * Kfull + kBase + schk;
  unsigned short* lA = &As[w * 512 + lane * 8];
  unsigned short* lB = &Bs[w * 512 + lane * 8];

  floatx4 acc[4] = {{0.f, 0.f, 0.f, 0.f}, {0.f, 0.f, 0.f, 0.f},
                    {0.f, 0.f, 0.f, 0.f}, {0.f, 0.f, 0.f, 0.f}};
  for (int k0 = 0; k0 < Klen; k0 += 32) {
    async16(lA, gA + k0);
    async16(lB, gB + k0);
    __syncthreads();
    short8 a = *(const short8*)&As[(w * 16 + c16) * 32 + quad * 8];
#pragma unroll
    for (int ntt = 0; ntt < 4; ++ntt) {
      short8 b = *(const short8*)&Bs[(ntt * 16 + c16) * 32 + quad * 8];
      acc[ntt] = MFMA(a, b, acc[ntt]);
    }
    __syncthreads();
  }
#pragma unroll
  for (int ntt = 0; ntt < 4; ++ntt) {
#pragma unroll
    for (int e = 0; e < 4; ++e) {
      int row = bm + w * 16 + quad * 4 + e;
      int col = bn + ntt * 16 + c16;
      float v = acc[ntt][e];
      if (z == 0) v += bias[col];
      if (gelu) v = 0.5f * v * (1.0f + erff(v * 0.70710678118654752f));
      if (outf) outf[(size_t)z * N * Nn + (size_t)row * Nn + col] = v;
      if (outb) outb[(size_t)row * Nn + col] = f2bf(v);
    }
  }
}

// ---- FFN2 GEMM (split-K x4) + atomic-tail: reduce + residual + LN2 --------
// grid (4, 32, 4). 16 blocks share row-stripe bm; last one (counter) re-reads
// the 4 partials and does the add_ln (bit-identical op order) for 64 rows.
__global__ __launch_bounds__(256) void k_mm_ffn2(
    const unsigned short* __restrict__ A,    // hb (N, DFF)
    const unsigned short* __restrict__ Bt,   // w2 (D, DFF)
    const float* __restrict__ bias,          // b2
    float* __restrict__ outf,                // tmp partials (4 x N*D)
    float* xio,                              // x in/out (residual, LN2 result)
    unsigned short* __restrict__ xbout,      // xb out
    const float* __restrict__ g, const float* __restrict__ b,
    int* __restrict__ cnt,                   // 32 counters (this layer)
    float* __restrict__ ppool) {             // last layer: 32x512 pool partials
  __shared__ unsigned short As[64 * 32];
  __shared__ unsigned short Bs[64 * 32];
  __shared__ int isLast;
  __shared__ float ws_[4][8], wq_[4][8];
  const int tid = threadIdx.x;
  const int w = tid >> 6, lane = tid & 63, quad = lane >> 4, c16 = lane & 15;
  const int bm = blockIdx.y * 64, bn = blockIdx.x * 64;
  const int z = blockIdx.z;
  const int kBase = z * (DFF / 4);
  const int srow = w * 16 + (lane >> 2);
  const int schk = (lane & 3) * 8;
  const unsigned short* gA = A + (size_t)(bm + srow) * DFF + kBase + schk;
  const unsigned short* gB = Bt + (size_t)(bn + srow) * DFF + kBase + schk;
  unsigned short* lA = &As[w * 512 + lane * 8];
  unsigned short* lB = &Bs[w * 512 + lane * 8];

  floatx4 acc[4] = {{0.f, 0.f, 0.f, 0.f}, {0.f, 0.f, 0.f, 0.f},
                    {0.f, 0.f, 0.f, 0.f}, {0.f, 0.f, 0.f, 0.f}};
  for (int k0 = 0; k0 < DFF / 4; k0 += 32) {
    async16(lA, gA + k0);
    async16(lB, gB + k0);
    __syncthreads();
    short8 a = *(const short8*)&As[(w * 16 + c16) * 32 + quad * 8];
#pragma unroll
    for (int ntt = 0; ntt < 4; ++ntt) {
      short8 bb = *(const short8*)&Bs[(ntt * 16 + c16) * 32 + quad * 8];
      acc[ntt] = MFMA(a, bb, acc[ntt]);
    }
    __syncthreads();
  }
#pragma unroll
  for (int ntt = 0; ntt < 4; ++ntt) {
#pragma unroll
    for (int e = 0; e < 4; ++e) {
      int row = bm + w * 16 + quad * 4 + e;
      int col = bn + ntt * 16 + c16;
      float v = acc[ntt][e];
      if (z == 0) v += bias[col];
      outf[(size_t)z * N * D + (size_t)row * D + col] = v;
    }
  }
  // release: make this block's partial visible, then count
  __threadfence();
  __syncthreads();
  if (tid == 0) {
    int old = atomicAdd(&cnt[blockIdx.y], 1);
    isLast = (old == 15);
  }
  __syncthreads();
  if (!isLast) return;
  __threadfence();  // acquire: see all 16 partials

  // tail: add residual + 4 partials, LN (same op order as former k_add_ln8)
  const int d = tid, wv = d >> 6;
  float psum = 0.f, pmax = -INFINITY;
  for (int rb = 0; rb < 8; ++rb) {
    const int row0 = bm + rb * 8;
    float t[8];
#pragma unroll
    for (int r = 0; r < 8; ++r) {
      size_t idx = (size_t)(row0 + r) * D + d;
      float tv = xio[idx];
#pragma unroll
      for (int i = 0; i < 4; ++i) tv += outf[(size_t)i * N * D + idx];
      t[r] = tv;
      float s = tv, q = tv * tv;
#pragma unroll
      for (int off = 1; off < 64; off <<= 1) {
        s += __shfl_xor(s, off);
        q += __shfl_xor(q, off);
      }
      if ((d & 63) == 0) { ws_[wv][r] = s; wq_[wv][r] = q; }
    }
    __syncthreads();
#pragma unroll
    for (int r = 0; r < 8; ++r) {
      float mean = (ws_[0][r] + ws_[1][r] + ws_[2][r] + ws_[3][r]) * (1.0f / D);
      float var = (wq_[0][r] + wq_[1][r] + wq_[2][r] + wq_[3][r]) * (1.0f / D) - mean * mean;
      float rs = rsqrtf(var + 1e-5f);
      float o = (t[r] - mean) * rs * g[d] + b[d];
      size_t idx = (size_t)(row0 + r) * D + d;
      xio[idx] = o;
      xbout[idx] = f2bf(o);
      psum += o;
      pmax = fmaxf(pmax, o);
    }
    __syncthreads();
  }
  if (ppool) {
    ppool[(size_t)blockIdx.y * 512 + d] = psum;
    ppool[(size_t)blockIdx.y * 512 + 256 + d] = pmax;
  }
}

// ---- fused QKV GEMM: Nn=768; writes qb (pre-scaled), kb, vt (D,N) bf16 ----
__global__ __launch_bounds__(256) void k_mm_qkv(const unsigned short* __restrict__ A,
                                                const unsigned short* __restrict__ Bt,
                                                unsigned short* __restrict__ qb,
                                                unsigned short* __restrict__ kb,
                                                unsigned short* __restrict__ vtb) {
  const int K = D;
  __shared__ unsigned short As[64 * 32];
  __shared__ unsigned short Bs[64 * 32];
  int tid = threadIdx.x;
  int w = tid >> 6, lane = tid & 63, quad = lane >> 4, c16 = lane & 15;
  int bm = blockIdx.y * 64, bn = blockIdx.x * 64;
  int srow = w * 16 + (lane >> 2);
  int schk = (lane & 3) * 8;
  const unsigned short* gA = A + (size_t)(bm + srow) * K + schk;
  const unsigned short* gB = Bt + (size_t)(bn + srow) * K + schk;
  unsigned short* lA = &As[w * 512 + lane * 8];
  unsigned short* lB = &Bs[w * 512 + lane * 8];

  floatx4 acc[4] = {{0.f, 0.f, 0.f, 0.f}, {0.f, 0.f, 0.f, 0.f},
                    {0.f, 0.f, 0.f, 0.f}, {0.f, 0.f, 0.f, 0.f}};
  for (int k0 = 0; k0 < K; k0 += 32) {
    async16(lA, gA + k0);
    async16(lB, gB + k0);
    __syncthreads();
    short8 a = *(const short8*)&As[(w * 16 + c16) * 32 + quad * 8];
#pragma unroll
    for (int ntt = 0; ntt < 4; ++ntt) {
      short8 b = *(const short8*)&Bs[(ntt * 16 + c16) * 32 + quad * 8];
      acc[ntt] = MFMA(a, b, acc[ntt]);
    }
    __syncthreads();
  }
#pragma unroll
  for (int ntt = 0; ntt < 4; ++ntt) {
#pragma unroll
    for (int e = 0; e < 4; ++e) {
      int row = bm + w * 16 + quad * 4 + e;
      int col = bn + ntt * 16 + c16;  // q:0-255, k:256-511, v:512-767
      float v = acc[ntt][e];
      if (col < 256) v *= QSCALE;
      unsigned short bv = f2bf(v);
      if (col < 512) {
        unsigned short* dst = (col < 256) ? qb : kb;
        dst[(size_t)row * D + (col & 255)] = bv;
      } else {
        vtb[(size_t)(col - 512) * N + row] = bv;
      }
    }
  }
}

// ---- pool phase 2: reduce 32 partials + project (WrT: contiguous rows) ----
__global__ __launch_bounds__(256) void k_pool2(const float* __restrict__ part,
                                               const float* __restrict__ WrT,
                                               const float* __restrict__ br,
                                               float* __restrict__ out) {
  __shared__ float pooled[2 * D];
  int d = threadIdx.x;
  float sum = 0.f, mx = -INFINITY;
  for (int b = 0; b < 32; ++b) {
    sum += part[(size_t)b * 512 + d];
    mx = fmaxf(mx, part[(size_t)b * 512 + 256 + d]);
  }
  pooled[d] = sum * (1.0f / N);
  pooled[D + d] = mx;
  __syncthreads();
  float acc = br[d];
  const float* wrow = WrT + (size_t)d * 512;
#pragma unroll 8
  for (int k2 = 0; k2 < 512; k2 += 4) {
    float4 wv = *(const float4*)(wrow + k2);
    acc += pooled[k2] * wv.x + pooled[k2 + 1] * wv.y +
           pooled[k2 + 2] * wv.z + pooled[k2 + 3] * wv.w;
  }
  out[d] = acc;
}

extern "C" void kernel_launch(void* const* d_in, const int* in_sizes, int n_in,
                              void* d_out, int out_size, void* d_ws, size_t ws_size,
                              hipStream_t stream) {
  const int* node_types = (const int*)d_in[0];
  const int* eidx = (const int*)d_in[1];
  const float* node_emb = (const float*)d_in[2];
  const float* Wq = (const float*)d_in[3];
  const float* Wk = (const float*)d_in[4];
  const float* Wv = (const float*)d_in[5];
  const float* Wo = (const float*)d_in[6];
  const float* bo = (const float*)d_in[7];
  const float* eb = (const float*)d_in[8];
  const float* W1 = (const float*)d_in[9];
  const float* b1 = (const float*)d_in[10];
  const float* W2 = (const float*)d_in[11];
  const float* b2 = (const float*)d_in[12];
  const float* g1 = (const float*)d_in[13];
  const float* be1 = (const float*)d_in[14];
  const float* g2 = (const float*)d_in[15];
  const float* be2 = (const float*)d_in[16];
  const float* Wr = (const float*)d_in[17];
  const float* br = (const float*)d_in[18];
  float* out = (float*)d_out;

  // workspace layout (tmp z>=2 FFN2 partials alias onto Opart: dead there)
  float* x = (float*)d_ws;                       // N*D fp32
  float* tmp = x + (size_t)N * D;                // 2*N*D fp32
  float* Opart = tmp + (size_t)2 * N * D;        // JC*N*D fp32
  float* lpart = Opart + (size_t)JC * N * D;     // JC*N*H
  float* ppool = lpart + (size_t)JC * N * H;     // 32*512
  float* WrT = ppool + 32 * 512;                 // 256*512 fp32
  int* cnt = (int*)(WrT + 256 * 512);            // L*32 counters
  unsigned short* xb = (unsigned short*)(cnt + 128);
  unsigned short* qb = xb + (size_t)N * D;
  unsigned short* kb = qb + (size_t)N * D;
  unsigned short* vtb = kb + (size_t)N * D;      // (D, N) head-major d
  unsigned short* hb = vtb + (size_t)N * D;      // N*DFF
  unsigned short* wqkvb = hb + (size_t)N * DFF;  // L x (768, 256)
  unsigned short* wob = wqkvb + (size_t)L * 768 * D;
  unsigned short* w1b = wob + (size_t)L * D * D;
  unsigned short* w2b = w1b + (size_t)L * DFF * D;
  unsigned int* e8 = (unsigned int*)(w2b + (size_t)L * D * DFF);  // N*N bytes

  k_setup<<<7297, 256, 0, stream>>>(eidx, e8, Wq, Wk, Wv, Wo, W1, W2, Wr,
                                    wqkvb, wob, w1b, w2b, WrT, cnt);
  k_embed_qkv<<<128, 512, 0, stream>>>(node_types, node_emb, wqkvb, x, qb, kb, vtb);

  for (int l = 0; l < L; ++l) {
    k_attn<<<dim3(N / 32, JC), 512, 0, stream>>>(qb, kb, vtb, e8,
                                                 eb + (size_t)l * NEDGE * H,
                                                 Opart, lpart);
    k_opln1<<<N / 16, 256, 0, stream>>>(Opart, lpart,
                                        wob + (size_t)l * D * D, bo + (size_t)l * D,
                                        g1 + (size_t)l * D, be1 + (size_t)l * D, x, xb);
    k_mm<<<dim3(DFF / 64, N / 64, 1), 256, 0, stream>>>(
        xb, w1b + (size_t)l * DFF * D, DFF, D, D, b1 + (size_t)l * DFF, 1,
        (float*)nullptr, hb);
    k_mm_ffn2<<<dim3(D / 64, N / 64, 4), 256, 0, stream>>>(
        hb, w2b + (size_t)l * D * DFF, b2 + (size_t)l * D, tmp,
        x, xb, g2 + (size_t)l * D, be2 + (size_t)l * D,
        cnt + l * 32, (l == L - 1) ? ppool : nullptr);
    if (l < L - 1) {
      k_mm_qkv<<<dim3(768 / 64, N / 64), 256, 0, stream>>>(
          xb, wqkvb + (size_t)(l + 1) * 768 * D, qb, kb, vtb);
    }
  }

  k_pool2<<<1, 256, 0, stream>>>(ppool, WrT, br, out);
}

// Round 8
// 418.433 us; speedup vs baseline: 1.8964x; 1.8964x over previous
//
#include <hip/hip_runtime.h>
#include <math.h>

#define N 2048
#define D 256
#define H 8
#define DK 32
#define L 4
#define DFF 1024
#define NEDGE 5
#define JC 8  // attention j-chunks (flash-decode split)

typedef short short8 __attribute__((ext_vector_type(8)));
typedef float floatx4 __attribute__((ext_vector_type(4)));

// Q pre-scale: 1/sqrt(DK) * log2(e)  (attention uses raw v_exp_f32 = exp2)
#define QSCALE 0.25503485657f
#define LOG2E 1.4426950408889634f

#define MFMA(a, b, c) __builtin_amdgcn_mfma_f32_16x16x32_bf16(a, b, c, 0, 0, 0)

#define AB_STR 280
#define PB_STR 72

__device__ __forceinline__ unsigned short f2bf(float f) {
  unsigned int u = __float_as_uint(f);
  u += 0x7fffu + ((u >> 16) & 1u);
  return (unsigned short)(u >> 16);
}

__device__ __forceinline__ float exp2_hw(float x) {
  float r;
  asm("v_exp_f32 %0, %1" : "=v"(r) : "v"(x));
  return r;
}

__device__ __forceinline__ unsigned int cvt_pk_bf16(float lo, float hi) {
  unsigned int r;
  asm("v_cvt_pk_bf16_f32 %0, %1, %2" : "=v"(r) : "v"(lo), "v"(hi));
  return r;
}

__device__ __forceinline__ void async16(unsigned short* lds, const unsigned short* g) {
  __builtin_amdgcn_global_load_lds(
      (const __attribute__((address_space(1))) unsigned int*)g,
      (__attribute__((address_space(3))) unsigned int*)lds, 16, 0, 0);
}

// ---- setup: e8 pack + weight transposes + WrT fp32 ------------------------
// blocks [0,4096): e8 pack; [4096,5120): Wq/Wk/Wv/Wo; [5120,6144): W1;
// [6144,7168): W2; [7168,7296): Wr fp32 transpose.
__global__ __launch_bounds__(256) void k_setup(
    const int* __restrict__ eidx, unsigned int* __restrict__ e8,
    const float* __restrict__ Wq, const float* __restrict__ Wk,
    const float* __restrict__ Wv, const float* __restrict__ Wo,
    const float* __restrict__ W1, const float* __restrict__ W2,
    const float* __restrict__ Wr,
    unsigned short* __restrict__ wqkvb, unsigned short* __restrict__ wob,
    unsigned short* __restrict__ w1b, unsigned short* __restrict__ w2b,
    float* __restrict__ WrT) {
  __shared__ float t[32][33];
  const int blk = blockIdx.x;
  const int tid = threadIdx.x;
  if (blk < 4096) {
    int i = blk * 256 + tid;  // word i = cols 4i..4i+3 of row i/512
    int4 v = ((const int4*)eidx)[i];
    e8[i] = (unsigned int)(v.x & 0xff) | ((unsigned int)(v.y & 0xff) << 8) |
            ((unsigned int)(v.z & 0xff) << 16) | ((unsigned int)(v.w & 0xff) << 24);
    return;
  }
  const int tx = tid & 31, ty = tid >> 5;
  if (blk >= 7168) {  // Wr (512,256) fp32 -> WrT (256,512) fp32
    int b5 = blk - 7168, bx = b5 & 7, by = b5 >> 3;
#pragma unroll
    for (int i = 0; i < 32; i += 8)
      t[ty + i][tx] = Wr[(size_t)(by * 32 + ty + i) * D + bx * 32 + tx];
    __syncthreads();
#pragma unroll
    for (int i = 0; i < 32; i += 8)
      WrT[(size_t)(bx * 32 + ty + i) * 512 + by * 32 + tx] = t[tx][ty + i];
    return;
  }
  const float* s;
  unsigned short* d;
  int rowOff, K_, N_, bx, by;
  if (blk < 5120) {
    int b2 = blk - 4096, z = b2 >> 6, rem = b2 & 63;
    int which = z >> 2, l = z & 3;
    s = (which == 0 ? Wq : which == 1 ? Wk : which == 2 ? Wv : Wo) + (size_t)l * D * D;
    if (which < 3) { d = wqkvb + (size_t)l * 768 * D; rowOff = which * 256; }
    else           { d = wob + (size_t)l * D * D;     rowOff = 0; }
    K_ = D; N_ = D; bx = rem & 7; by = rem >> 3;
  } else if (blk < 6144) {
    int b3 = blk - 5120, l = b3 >> 8, rem = b3 & 255;
    s = W1 + (size_t)l * D * DFF; d = w1b + (size_t)l * DFF * D; rowOff = 0;
    K_ = D; N_ = DFF; bx = rem & 31; by = rem >> 5;
  } else {
    int b4 = blk - 6144, l = b4 >> 8, rem = b4 & 255;
    s = W2 + (size_t)l * DFF * D; d = w2b + (size_t)l * D * DFF; rowOff = 0;
    K_ = DFF; N_ = D; bx = rem & 7; by = rem >> 3;
  }
  int n0 = bx * 32, k0 = by * 32;
#pragma unroll
  for (int i = 0; i < 32; i += 8) t[ty + i][tx] = s[(size_t)(k0 + ty + i) * N_ + n0 + tx];
  __syncthreads();
#pragma unroll
  for (int i = 0; i < 32; i += 8)
    d[(size_t)(rowOff + n0 + ty + i) * K_ + k0 + tx] = f2bf(t[tx][ty + i]);
}

// ---- qkv tail for 8-wave/16-row blocks (embed kernel only) ----------------
__device__ __forceinline__ void qkv_from_Ab8(
    const unsigned short* Ab, const unsigned short* __restrict__ wqkv,
    unsigned short* __restrict__ qb, unsigned short* __restrict__ kb,
    unsigned short* __restrict__ vtb, int r0, int w, int quad, int c16) {
  short8 af[8];
#pragma unroll
  for (int k = 0; k < 8; ++k)
    af[k] = *(const short8*)&Ab[c16 * AB_STR + k * 32 + quad * 8];
#pragma unroll
  for (int tp = 0; tp < 3; ++tp) {
    const int cb0 = (w * 6 + tp * 2) * 16 + c16;
    const int cb1 = cb0 + 16;
    const unsigned short* B0 = wqkv + (size_t)cb0 * D + quad * 8;
    const unsigned short* B1 = wqkv + (size_t)cb1 * D + quad * 8;
    floatx4 a0 = {0.f, 0.f, 0.f, 0.f}, a1 = {0.f, 0.f, 0.f, 0.f};
#pragma unroll
    for (int k = 0; k < 8; ++k) {
      a0 = MFMA(af[k], *(const short8*)(B0 + k * 32), a0);
      a1 = MFMA(af[k], *(const short8*)(B1 + k * 32), a1);
    }
#pragma unroll
    for (int e = 0; e < 4; ++e) {
      const int grow = r0 + quad * 4 + e;
#pragma unroll
      for (int half = 0; half < 2; ++half) {
        int gc = half ? cb1 : cb0;
        float v = half ? a1[e] : a0[e];
        if (gc < 256)      qb[(size_t)grow * D + gc] = f2bf(v * QSCALE);
        else if (gc < 512) kb[(size_t)grow * D + (gc - 256)] = f2bf(v);
        else               vtb[(size_t)(gc - 512) * N + grow] = f2bf(v);
      }
    }
  }
}

// ---- embed + layer-0 QKV --------------------------------------------------
__global__ __launch_bounds__(512) void k_embed_qkv(
    const int* __restrict__ nt, const float* __restrict__ emb,
    const unsigned short* __restrict__ wqkv0, float* __restrict__ x,
    unsigned short* __restrict__ qb, unsigned short* __restrict__ kb,
    unsigned short* __restrict__ vtb) {
  __shared__ __align__(16) unsigned short Ab[16 * AB_STR];
  const int tid = threadIdx.x;
  const int w = tid >> 6, lane = tid & 63, quad = lane >> 4, c16 = lane & 15;
  const int r0 = blockIdx.x * 16;
  {
    const int r = tid >> 5, cb = (tid & 31) * 8;
    const int ty = nt[r0 + r];
    float4 a = *(const float4*)&emb[(size_t)ty * D + cb];
    float4 b = *(const float4*)&emb[(size_t)ty * D + cb + 4];
    *(float4*)&x[(size_t)(r0 + r) * D + cb] = a;
    *(float4*)&x[(size_t)(r0 + r) * D + cb + 4] = b;
    Ab[r * AB_STR + cb + 0] = f2bf(a.x); Ab[r * AB_STR + cb + 1] = f2bf(a.y);
    Ab[r * AB_STR + cb + 2] = f2bf(a.z); Ab[r * AB_STR + cb + 3] = f2bf(a.w);
    Ab[r * AB_STR + cb + 4] = f2bf(b.x); Ab[r * AB_STR + cb + 5] = f2bf(b.y);
    Ab[r * AB_STR + cb + 6] = f2bf(b.z); Ab[r * AB_STR + cb + 7] = f2bf(b.w);
  }
  __syncthreads();
  qkv_from_Ab8(Ab, wqkv0, qb, kb, vtb, r0, w, quad, c16);
}

// ---- MFMA flash attention: QBLK=32, JC=8, m=0, contiguous-P ---------------
// grid (N/32, JC) = (64, 8); block 512 (8 waves); wave h = head h, 32 Q-rows
// (two 16-row groups A/B sharing K/V fragments), 256 j-cols.
__global__ __launch_bounds__(512) void k_attn(const unsigned short* __restrict__ qb,
                                              const unsigned short* __restrict__ kb,
                                              const unsigned short* __restrict__ vt,
                                              const unsigned int* __restrict__ e8,
                                              const float* __restrict__ eb,
                                              float* __restrict__ Opart,
                                              float* __restrict__ lpart) {
  __shared__ __align__(16) unsigned short Pb[H][32 * PB_STR];
  __shared__ float ebh[H][NEDGE];
  __shared__ unsigned int e8s[32][65];
  const int tid = threadIdx.x;
  const int h = tid >> 6;
  const int lane = tid & 63;
  const int quad = lane >> 4;
  const int c16 = lane & 15;
  const int r0 = blockIdx.x * 32;
  const int jc = blockIdx.y;

  if (tid < NEDGE * H) ebh[tid % H][tid / H] = eb[tid] * LOG2E;
  for (int i = tid; i < 32 * 64; i += 512) {
    int r = i >> 6, ww = i & 63;
    e8s[r][ww] = e8[(size_t)(r0 + r) * (N / 4) + jc * 64 + ww];
  }
  __syncthreads();

  short8 aqA = *(const short8*)&qb[(size_t)(r0 + c16) * D + h * DK + quad * 8];
  short8 aqB = *(const short8*)&qb[(size_t)(r0 + 16 + c16) * D + h * DK + quad * 8];

  float lrowA[4] = {0.f, 0.f, 0.f, 0.f};
  float lrowB[4] = {0.f, 0.f, 0.f, 0.f};
  floatx4 O0A = {0.f, 0.f, 0.f, 0.f}, O1A = {0.f, 0.f, 0.f, 0.f};
  floatx4 O0B = {0.f, 0.f, 0.f, 0.f}, O1B = {0.f, 0.f, 0.f, 0.f};

  for (int g = 0; g < (N / JC) / 64; ++g) {
    const int j0 = jc * (N / JC) + g * 64;
    short8 bk[4];
#pragma unroll
    for (int t = 0; t < 4; ++t)
      bk[t] = *(const short8*)&kb[(size_t)(j0 + c16 * 4 + t) * D + h * DK + quad * 8];
    {
      unsigned int wrd[4];
#pragma unroll
      for (int e = 0; e < 4; ++e) wrd[e] = e8s[quad * 4 + e][g * 16 + c16];
      floatx4 Sc[4];
#pragma unroll
      for (int t = 0; t < 4; ++t) {
        floatx4 cbv;
#pragma unroll
        for (int e = 0; e < 4; ++e) cbv[e] = ebh[h][(wrd[e] >> (8 * t)) & 0xff];
        Sc[t] = MFMA(aqA, bk[t], cbv);
      }
      float p[4][4];
#pragma unroll
      for (int e = 0; e < 4; ++e) {
#pragma unroll
        for (int t = 0; t < 4; ++t) p[t][e] = exp2_hw(Sc[t][e]);
        lrowA[e] += (p[0][e] + p[1][e]) + (p[2][e] + p[3][e]);
      }
#pragma unroll
      for (int e = 0; e < 4; ++e) {
        uint2 u;
        u.x = cvt_pk_bf16(p[0][e], p[1][e]);
        u.y = cvt_pk_bf16(p[2][e], p[3][e]);
        *(uint2*)&Pb[h][(quad * 4 + e) * PB_STR + c16 * 4] = u;
      }
    }
    {
      unsigned int wrd[4];
#pragma unroll
      for (int e = 0; e < 4; ++e) wrd[e] = e8s[16 + quad * 4 + e][g * 16 + c16];
      floatx4 Sc[4];
#pragma unroll
      for (int t = 0; t < 4; ++t) {
        floatx4 cbv;
#pragma unroll
        for (int e = 0; e < 4; ++e) cbv[e] = ebh[h][(wrd[e] >> (8 * t)) & 0xff];
        Sc[t] = MFMA(aqB, bk[t], cbv);
      }
      float p[4][4];
#pragma unroll
      for (int e = 0; e < 4; ++e) {
#pragma unroll
        for (int t = 0; t < 4; ++t) p[t][e] = exp2_hw(Sc[t][e]);
        lrowB[e] += (p[0][e] + p[1][e]) + (p[2][e] + p[3][e]);
      }
#pragma unroll
      for (int e = 0; e < 4; ++e) {
        uint2 u;
        u.x = cvt_pk_bf16(p[0][e], p[1][e]);
        u.y = cvt_pk_bf16(p[2][e], p[3][e]);
        *(uint2*)&Pb[h][(16 + quad * 4 + e) * PB_STR + c16 * 4] = u;
      }
    }
    asm volatile("" ::: "memory");
#pragma unroll
    for (int jj = 0; jj < 2; ++jj) {
      short8 apA = *(const short8*)&Pb[h][c16 * PB_STR + jj * 32 + quad * 8];
      short8 apB = *(const short8*)&Pb[h][(16 + c16) * PB_STR + jj * 32 + quad * 8];
      short8 bv0 = *(const short8*)&vt[(size_t)(h * DK + c16) * N + j0 + jj * 32 + quad * 8];
      short8 bv1 = *(const short8*)&vt[(size_t)(h * DK + 16 + c16) * N + j0 + jj * 32 + quad * 8];
      O0A = MFMA(apA, bv0, O0A); O1A = MFMA(apA, bv1, O1A);
      O0B = MFMA(apB, bv0, O0B); O1B = MFMA(apB, bv1, O1B);
    }
    asm volatile("" ::: "memory");
  }

#pragma unroll
  for (int e = 0; e < 4; ++e) {
    float va = lrowA[e], vb = lrowB[e];
    va += __shfl_xor(va, 1); va += __shfl_xor(va, 2);
    va += __shfl_xor(va, 4); va += __shfl_xor(va, 8);
    vb += __shfl_xor(vb, 1); vb += __shfl_xor(vb, 2);
    vb += __shfl_xor(vb, 4); vb += __shfl_xor(vb, 8);
    lrowA[e] = va; lrowB[e] = vb;
  }
#pragma unroll
  for (int e = 0; e < 4; ++e) {
    int rowA = r0 + quad * 4 + e, rowB = rowA + 16;
    size_t obA = ((size_t)jc * N + rowA) * D + h * DK;
    size_t obB = ((size_t)jc * N + rowB) * D + h * DK;
    Opart[obA + c16] = O0A[e];
    Opart[obA + 16 + c16] = O1A[e];
    Opart[obB + c16] = O0B[e];
    Opart[obB + 16 + c16] = O1B[e];
    if (c16 == 0) {
      lpart[((size_t)jc * N + rowA) * H + h] = lrowA[e];
      lpart[((size_t)jc * N + rowB) * H + h] = lrowB[e];
    }
  }
}

// ---- fused: attn-combine -> out-proj GEMM -> +bo +res -> LN1 -> x, xb -----
// grid N/16 = 128 blocks x 256 thr (4 waves). Block owns 16 COMPLETE rows;
// wave w covers cols 64w..64w+63 (4 n-tiles). No split-K; LN in epilogue.
__global__ __launch_bounds__(256) void k_opln1(
    const float* __restrict__ Opart, const float* __restrict__ lpart,
    const unsigned short* __restrict__ wo, const float* __restrict__ bo,
    const float* __restrict__ g1, const float* __restrict__ be1,
    float* __restrict__ x, unsigned short* __restrict__ xb) {
  __shared__ __align__(16) unsigned short Ab[16 * AB_STR];
  __shared__ __align__(16) float Xr[16][260];
  __shared__ float linv[16][8];
  __shared__ float red1[4][16], red2[4][16], mu[16], rsg[16];
  const int tid = threadIdx.x;
  const int w = tid >> 6, lane = tid & 63, quad = lane >> 4, c16 = lane & 15;
  const int r0 = blockIdx.x * 16;

  if (tid < 128) {
    int r = tid >> 3, hh = tid & 7;
    float ls = 0.f;
#pragma unroll
    for (int c = 0; c < JC; ++c) ls += lpart[((size_t)c * N + r0 + r) * H + hh];
    linv[r][hh] = 1.f / ls;
  }
  for (int i = tid; i < 16 * 64; i += 256) {
    int r = i >> 6, c4 = (i & 63) * 4;
    *(float4*)&Xr[r][c4] = *(const float4*)&x[(size_t)(r0 + r) * D + c4];
  }
  __syncthreads();
  {
    const int r = tid >> 4, c0 = (tid & 15) * 16;
    float o[16];
#pragma unroll
    for (int j = 0; j < 16; ++j) o[j] = 0.f;
#pragma unroll
    for (int c = 0; c < JC; ++c) {
      const float* p = &Opart[((size_t)c * N + r0 + r) * D + c0];
#pragma unroll
      for (int j4 = 0; j4 < 4; ++j4) {
        float4 pv = *(const float4*)(p + j4 * 4);
        o[j4 * 4 + 0] += pv.x; o[j4 * 4 + 1] += pv.y;
        o[j4 * 4 + 2] += pv.z; o[j4 * 4 + 3] += pv.w;
      }
    }
    const float iv = linv[r][c0 >> 5];
#pragma unroll
    for (int j = 0; j < 16; j += 2)
      *(unsigned int*)&Ab[r * AB_STR + c0 + j] = cvt_pk_bf16(o[j] * iv, o[j + 1] * iv);
  }
  __syncthreads();

  short8 af[8];
#pragma unroll
  for (int k = 0; k < 8; ++k)
    af[k] = *(const short8*)&Ab[c16 * AB_STR + k * 32 + quad * 8];
  floatx4 acc[4] = {{0.f, 0.f, 0.f, 0.f}, {0.f, 0.f, 0.f, 0.f},
                    {0.f, 0.f, 0.f, 0.f}, {0.f, 0.f, 0.f, 0.f}};
#pragma unroll
  for (int ntt = 0; ntt < 4; ++ntt) {
    const int col = w * 64 + ntt * 16 + c16;
    const unsigned short* B = wo + (size_t)col * D + quad * 8;
#pragma unroll
    for (int k = 0; k < 8; ++k) acc[ntt] = MFMA(af[k], *(const short8*)(B + k * 32), acc[ntt]);
  }
  float v[4][4];
#pragma unroll
  for (int e = 0; e < 4; ++e) {
    const int row = quad * 4 + e;
    float s = 0.f, q = 0.f;
#pragma unroll
    for (int ntt = 0; ntt < 4; ++ntt) {
      const int col = w * 64 + ntt * 16 + c16;
      float vv = acc[ntt][e] + bo[col] + Xr[row][col];
      v[ntt][e] = vv;
      s += vv; q += vv * vv;
    }
    s += __shfl_xor(s, 1); s += __shfl_xor(s, 2);
    s += __shfl_xor(s, 4); s += __shfl_xor(s, 8);
    q += __shfl_xor(q, 1); q += __shfl_xor(q, 2);
    q += __shfl_xor(q, 4); q += __shfl_xor(q, 8);
    if (c16 == 0) { red1[w][row] = s; red2[w][row] = q; }
  }
  __syncthreads();
  if (tid < 16) {
    float m = red1[0][tid] + red1[1][tid] + red1[2][tid] + red1[3][tid];
    float q = red2[0][tid] + red2[1][tid] + red2[2][tid] + red2[3][tid];
    m *= (1.f / 256.f);
    q = q * (1.f / 256.f) - m * m;
    mu[tid] = m;
    rsg[tid] = rsqrtf(q + 1e-5f);
  }
  __syncthreads();
#pragma unroll
  for (int e = 0; e < 4; ++e) {
    const int row = quad * 4 + e;
#pragma unroll
    for (int ntt = 0; ntt < 4; ++ntt) {
      const int col = w * 64 + ntt * 16 + c16;
      float o = (v[ntt][e] - mu[row]) * rsg[row] * g1[col] + be1[col];
      x[(size_t)(r0 + row) * D + col] = o;
      xb[(size_t)(r0 + row) * D + col] = f2bf(o);
    }
  }
}

// ---- bf16 MFMA GEMM: C = A(M,K) @ Bt(Nn,K)^T [+bias][+gelu] ---------------
// blockIdx.z = K-split chunk; z>0 writes partial (no bias) at outf + z*N*Nn.
__global__ __launch_bounds__(256) void k_mm(const unsigned short* __restrict__ A,
                                            const unsigned short* __restrict__ Bt,
                                            int Nn, int Kfull, int Klen,
                                            const float* __restrict__ bias,
                                            int gelu,
                                            float* __restrict__ outf,
                                            unsigned short* __restrict__ outb) {
  __shared__ unsigned short As[64 * 32];
  __shared__ unsigned short Bs[64 * 32];
  int tid = threadIdx.x;
  int w = tid >> 6, lane = tid & 63, quad = lane >> 4, c16 = lane & 15;
  int bm = blockIdx.y * 64, bn = blockIdx.x * 64;
  int z = blockIdx.z;
  int kBase = z * Klen;
  int srow = w * 16 + (lane >> 2);
  int schk = (lane & 3) * 8;
  const unsigned short* gA = A + (size_t)(bm + srow) * Kfull + kBase + schk;
  const unsigned short* gB = Bt + (size_t)(bn + srow) * Kfull + kBase + schk;
  unsigned short* lA = &As[w * 512 + lane * 8];
  unsigned short* lB = &Bs[w * 512 + lane * 8];

  floatx4 acc[4] = {{0.f, 0.f, 0.f, 0.f}, {0.f, 0.f, 0.f, 0.f},
                    {0.f, 0.f, 0.f, 0.f}, {0.f, 0.f, 0.f, 0.f}};
  for (int k0 = 0; k0 < Klen; k0 += 32) {
    async16(lA, gA + k0);
    async16(lB, gB + k0);
    __syncthreads();
    short8 a = *(const short8*)&As[(w * 16 + c16) * 32 + quad * 8];
#pragma unroll
    for (int ntt = 0; ntt < 4; ++ntt) {
      short8 b = *(const short8*)&Bs[(ntt * 16 + c16) * 32 + quad * 8];
      acc[ntt] = MFMA(a, b, acc[ntt]);
    }
    __syncthreads();
  }
#pragma unroll
  for (int ntt = 0; ntt < 4; ++ntt) {
#pragma unroll
    for (int e = 0; e < 4; ++e) {
      int row = bm + w * 16 + quad * 4 + e;
      int col = bn + ntt * 16 + c16;
      float v = acc[ntt][e];
      if (z == 0) v += bias[col];
      if (gelu) v = 0.5f * v * (1.0f + erff(v * 0.70710678118654752f));
      if (outf) outf[(size_t)z * N * Nn + (size_t)row * Nn + col] = v;
      if (outb) outb[(size_t)row * Nn + col] = f2bf(v);
    }
  }
}

// ---- fused QKV GEMM: Nn=768; writes qb (pre-scaled), kb, vt (D,N) bf16 ----
__global__ __launch_bounds__(256) void k_mm_qkv(const unsigned short* __restrict__ A,
                                                const unsigned short* __restrict__ Bt,
                                                unsigned short* __restrict__ qb,
                                                unsigned short* __restrict__ kb,
                                                unsigned short* __restrict__ vtb) {
  const int K = D;
  __shared__ unsigned short As[64 * 32];
  __shared__ unsigned short Bs[64 * 32];
  int tid = threadIdx.x;
  int w = tid >> 6, lane = tid & 63, quad = lane >> 4, c16 = lane & 15;
  int bm = blockIdx.y * 64, bn = blockIdx.x * 64;
  int srow = w * 16 + (lane >> 2);
  int schk = (lane & 3) * 8;
  const unsigned short* gA = A + (size_t)(bm + srow) * K + schk;
  const unsigned short* gB = Bt + (size_t)(bn + srow) * K + schk;
  unsigned short* lA = &As[w * 512 + lane * 8];
  unsigned short* lB = &Bs[w * 512 + lane * 8];

  floatx4 acc[4] = {{0.f, 0.f, 0.f, 0.f}, {0.f, 0.f, 0.f, 0.f},
                    {0.f, 0.f, 0.f, 0.f}, {0.f, 0.f, 0.f, 0.f}};
  for (int k0 = 0; k0 < K; k0 += 32) {
    async16(lA, gA + k0);
    async16(lB, gB + k0);
    __syncthreads();
    short8 a = *(const short8*)&As[(w * 16 + c16) * 32 + quad * 8];
#pragma unroll
    for (int ntt = 0; ntt < 4; ++ntt) {
      short8 b = *(const short8*)&Bs[(ntt * 16 + c16) * 32 + quad * 8];
      acc[ntt] = MFMA(a, b, acc[ntt]);
    }
    __syncthreads();
  }
#pragma unroll
  for (int ntt = 0; ntt < 4; ++ntt) {
#pragma unroll
    for (int e = 0; e < 4; ++e) {
      int row = bm + w * 16 + quad * 4 + e;
      int col = bn + ntt * 16 + c16;  // q:0-255, k:256-511, v:512-767
      float v = acc[ntt][e];
      if (col < 256) v *= QSCALE;
      unsigned short bv = f2bf(v);
      if (col < 512) {
        unsigned short* dst = (col < 256) ? qb : kb;
        dst[(size_t)row * D + (col & 255)] = bv;
      } else {
        vtb[(size_t)(col - 512) * N + row] = bv;
      }
    }
  }
}

// ---- residual + 4 partials + LN, 8 rows/block; optional pool partials -----
__global__ __launch_bounds__(256) void k_add_ln8(const float* __restrict__ x,
                                                 const float* __restrict__ y,
                                                 const float* __restrict__ g,
                                                 const float* __restrict__ b,
                                                 float* __restrict__ outx,
                                                 unsigned short* __restrict__ outb,
                                                 float* __restrict__ ppool) {
  __shared__ float ws_[4][8], wq_[4][8];
  const int d = threadIdx.x, wv = d >> 6;
  const int row0 = blockIdx.x * 8;
  float t[8];
#pragma unroll
  for (int r = 0; r < 8; ++r) {
    size_t idx = (size_t)(row0 + r) * D + d;
    float tv = x[idx];
#pragma unroll
    for (int i = 0; i < 4; ++i) tv += y[(size_t)i * N * D + idx];
    t[r] = tv;
    float s = tv, q = tv * tv;
#pragma unroll
    for (int off = 1; off < 64; off <<= 1) {
      s += __shfl_xor(s, off);
      q += __shfl_xor(q, off);
    }
    if ((d & 63) == 0) { ws_[wv][r] = s; wq_[wv][r] = q; }
  }
  __syncthreads();
  float psum = 0.f, pmax = -INFINITY;
#pragma unroll
  for (int r = 0; r < 8; ++r) {
    float mean = (ws_[0][r] + ws_[1][r] + ws_[2][r] + ws_[3][r]) * (1.0f / D);
    float var = (wq_[0][r] + wq_[1][r] + wq_[2][r] + wq_[3][r]) * (1.0f / D) - mean * mean;
    float rs = rsqrtf(var + 1e-5f);
    float o = (t[r] - mean) * rs * g[d] + b[d];
    size_t idx = (size_t)(row0 + r) * D + d;
    outx[idx] = o;
    outb[idx] = f2bf(o);
    psum += o;
    pmax = fmaxf(pmax, o);
  }
  if (ppool) {
    ppool[(size_t)blockIdx.x * 512 + d] = psum;
    ppool[(size_t)blockIdx.x * 512 + 256 + d] = pmax;
  }
}

// ---- pool phase 2: reduce 256 partials + project (WrT contiguous rows) ----
__global__ __launch_bounds__(256) void k_pool2(const float* __restrict__ part,
                                               const float* __restrict__ WrT,
                                               const float* __restrict__ br,
                                               float* __restrict__ out) {
  __shared__ float pooled[2 * D];
  int d = threadIdx.x;
  float sum = 0.f, mx = -INFINITY;
  for (int b = 0; b < 256; ++b) {
    sum += part[(size_t)b * 512 + d];
    mx = fmaxf(mx, part[(size_t)b * 512 + 256 + d]);
  }
  pooled[d] = sum * (1.0f / N);
  pooled[D + d] = mx;
  __syncthreads();
  float acc = br[d];
  const float* wrow = WrT + (size_t)d * 512;
#pragma unroll 8
  for (int k2 = 0; k2 < 512; k2 += 4) {
    float4 wv = *(const float4*)(wrow + k2);
    acc += pooled[k2] * wv.x + pooled[k2 + 1] * wv.y +
           pooled[k2 + 2] * wv.z + pooled[k2 + 3] * wv.w;
  }
  out[d] = acc;
}

extern "C" void kernel_launch(void* const* d_in, const int* in_sizes, int n_in,
                              void* d_out, int out_size, void* d_ws, size_t ws_size,
                              hipStream_t stream) {
  const int* node_types = (const int*)d_in[0];
  const int* eidx = (const int*)d_in[1];
  const float* node_emb = (const float*)d_in[2];
  const float* Wq = (const float*)d_in[3];
  const float* Wk = (const float*)d_in[4];
  const float* Wv = (const float*)d_in[5];
  const float* Wo = (const float*)d_in[6];
  const float* bo = (const float*)d_in[7];
  const float* eb = (const float*)d_in[8];
  const float* W1 = (const float*)d_in[9];
  const float* b1 = (const float*)d_in[10];
  const float* W2 = (const float*)d_in[11];
  const float* b2 = (const float*)d_in[12];
  const float* g1 = (const float*)d_in[13];
  const float* be1 = (const float*)d_in[14];
  const float* g2 = (const float*)d_in[15];
  const float* be2 = (const float*)d_in[16];
  const float* Wr = (const float*)d_in[17];
  const float* br = (const float*)d_in[18];
  float* out = (float*)d_out;

  // workspace layout (tmp z>=2 FFN2 partials alias onto Opart: dead there)
  float* x = (float*)d_ws;                       // N*D fp32
  float* tmp = x + (size_t)N * D;                // 2*N*D fp32
  float* Opart = tmp + (size_t)2 * N * D;        // JC*N*D fp32
  float* lpart = Opart + (size_t)JC * N * D;     // JC*N*H
  float* ppool = lpart + (size_t)JC * N * H;     // 256*512
  float* WrT = ppool + 256 * 512;                // 256*512 fp32
  unsigned short* xb = (unsigned short*)(WrT + 256 * 512);
  unsigned short* qb = xb + (size_t)N * D;
  unsigned short* kb = qb + (size_t)N * D;
  unsigned short* vtb = kb + (size_t)N * D;      // (D, N) head-major d
  unsigned short* hb = vtb + (size_t)N * D;      // N*DFF
  unsigned short* wqkvb = hb + (size_t)N * DFF;  // L x (768, 256)
  unsigned short* wob = wqkvb + (size_t)L * 768 * D;
  unsigned short* w1b = wob + (size_t)L * D * D;
  unsigned short* w2b = w1b + (size_t)L * DFF * D;
  unsigned int* e8 = (unsigned int*)(w2b + (size_t)L * D * DFF);  // N*N bytes

  k_setup<<<7296, 256, 0, stream>>>(eidx, e8, Wq, Wk, Wv, Wo, W1, W2, Wr,
                                    wqkvb, wob, w1b, w2b, WrT);
  k_embed_qkv<<<128, 512, 0, stream>>>(node_types, node_emb, wqkvb, x, qb, kb, vtb);

  for (int l = 0; l < L; ++l) {
    k_attn<<<dim3(N / 32, JC), 512, 0, stream>>>(qb, kb, vtb, e8,
                                                 eb + (size_t)l * NEDGE * H,
                                                 Opart, lpart);
    k_opln1<<<N / 16, 256, 0, stream>>>(Opart, lpart,
                                        wob + (size_t)l * D * D, bo + (size_t)l * D,
                                        g1 + (size_t)l * D, be1 + (size_t)l * D, x, xb);
    k_mm<<<dim3(DFF / 64, N / 64, 1), 256, 0, stream>>>(
        xb, w1b + (size_t)l * DFF * D, DFF, D, D, b1 + (size_t)l * DFF, 1,
        (float*)nullptr, hb);
    k_mm<<<dim3(D / 64, N / 64, 4), 256, 0, stream>>>(
        hb, w2b + (size_t)l * D * DFF, D, DFF, DFF / 4, b2 + (size_t)l * D, 0,
        tmp, (unsigned short*)nullptr);
    k_add_ln8<<<N / 8, 256, 0, stream>>>(x, tmp, g2 + (size_t)l * D, be2 + (size_t)l * D,
                                         x, xb, (l == L - 1) ? ppool : nullptr);
    if (l < L - 1) {
      k_mm_qkv<<<dim3(768 / 64, N / 64), 256, 0, stream>>>(
          xb, wqkvb + (size_t)(l + 1) * 768 * D, qb, kb, vtb);
    }
  }

  k_pool2<<<1, 256, 0, stream>>>(ppool, WrT, br, out);
}

// Round 9
// 416.695 us; speedup vs baseline: 1.9043x; 1.0042x over previous
//
#include <hip/hip_runtime.h>
#include <math.h>

#define N 2048
#define D 256
#define H 8
#define DK 32
#define L 4
#define DFF 1024
#define NEDGE 5
#define JC 8  // attention j-chunks (flash-decode split)

typedef short short8 __attribute__((ext_vector_type(8)));
typedef float floatx4 __attribute__((ext_vector_type(4)));

// Q pre-scale: 1/sqrt(DK) * log2(e)  (attention uses raw v_exp_f32 = exp2)
#define QSCALE 0.25503485657f
#define LOG2E 1.4426950408889634f

#define MFMA(a, b, c) __builtin_amdgcn_mfma_f32_16x16x32_bf16(a, b, c, 0, 0, 0)

#define AB_STR 280   // (280*2/4)%32 = 12-bank row stride -> 2-way alias (free)
#define PB_STR 72
#define HS_STR 1048  // same 12-bank residue as AB_STR

__device__ __forceinline__ unsigned short f2bf(float f) {
  unsigned int u = __float_as_uint(f);
  u += 0x7fffu + ((u >> 16) & 1u);
  return (unsigned short)(u >> 16);
}

__device__ __forceinline__ float exp2_hw(float x) {
  float r;
  asm("v_exp_f32 %0, %1" : "=v"(r) : "v"(x));
  return r;
}

__device__ __forceinline__ unsigned int cvt_pk_bf16(float lo, float hi) {
  unsigned int r;
  asm("v_cvt_pk_bf16_f32 %0, %1, %2" : "=v"(r) : "v"(lo), "v"(hi));
  return r;
}

__device__ __forceinline__ void async16(unsigned short* lds, const unsigned short* g) {
  __builtin_amdgcn_global_load_lds(
      (const __attribute__((address_space(1))) unsigned int*)g,
      (__attribute__((address_space(3))) unsigned int*)lds, 16, 0, 0);
}

// ---- setup: e8 pack + weight transposes + WrT fp32 ------------------------
__global__ __launch_bounds__(256) void k_setup(
    const int* __restrict__ eidx, unsigned int* __restrict__ e8,
    const float* __restrict__ Wq, const float* __restrict__ Wk,
    const float* __restrict__ Wv, const float* __restrict__ Wo,
    const float* __restrict__ W1, const float* __restrict__ W2,
    const float* __restrict__ Wr,
    unsigned short* __restrict__ wqkvb, unsigned short* __restrict__ wob,
    unsigned short* __restrict__ w1b, unsigned short* __restrict__ w2b,
    float* __restrict__ WrT) {
  __shared__ float t[32][33];
  const int blk = blockIdx.x;
  const int tid = threadIdx.x;
  if (blk < 4096) {
    int i = blk * 256 + tid;  // word i = cols 4i..4i+3 of row i/512
    int4 v = ((const int4*)eidx)[i];
    e8[i] = (unsigned int)(v.x & 0xff) | ((unsigned int)(v.y & 0xff) << 8) |
            ((unsigned int)(v.z & 0xff) << 16) | ((unsigned int)(v.w & 0xff) << 24);
    return;
  }
  const int tx = tid & 31, ty = tid >> 5;
  if (blk >= 7168) {  // Wr (512,256) fp32 -> WrT (256,512) fp32
    int b5 = blk - 7168, bx = b5 & 7, by = b5 >> 3;
#pragma unroll
    for (int i = 0; i < 32; i += 8)
      t[ty + i][tx] = Wr[(size_t)(by * 32 + ty + i) * D + bx * 32 + tx];
    __syncthreads();
#pragma unroll
    for (int i = 0; i < 32; i += 8)
      WrT[(size_t)(bx * 32 + ty + i) * 512 + by * 32 + tx] = t[tx][ty + i];
    return;
  }
  const float* s;
  unsigned short* d;
  int rowOff, K_, N_, bx, by;
  if (blk < 5120) {
    int b2 = blk - 4096, z = b2 >> 6, rem = b2 & 63;
    int which = z >> 2, l = z & 3;
    s = (which == 0 ? Wq : which == 1 ? Wk : which == 2 ? Wv : Wo) + (size_t)l * D * D;
    if (which < 3) { d = wqkvb + (size_t)l * 768 * D; rowOff = which * 256; }
    else           { d = wob + (size_t)l * D * D;     rowOff = 0; }
    K_ = D; N_ = D; bx = rem & 7; by = rem >> 3;
  } else if (blk < 6144) {
    int b3 = blk - 5120, l = b3 >> 8, rem = b3 & 255;
    s = W1 + (size_t)l * D * DFF; d = w1b + (size_t)l * DFF * D; rowOff = 0;
    K_ = D; N_ = DFF; bx = rem & 31; by = rem >> 5;
  } else {
    int b4 = blk - 6144, l = b4 >> 8, rem = b4 & 255;
    s = W2 + (size_t)l * DFF * D; d = w2b + (size_t)l * D * DFF; rowOff = 0;
    K_ = DFF; N_ = D; bx = rem & 7; by = rem >> 3;
  }
  int n0 = bx * 32, k0 = by * 32;
#pragma unroll
  for (int i = 0; i < 32; i += 8) t[ty + i][tx] = s[(size_t)(k0 + ty + i) * N_ + n0 + tx];
  __syncthreads();
#pragma unroll
  for (int i = 0; i < 32; i += 8)
    d[(size_t)(rowOff + n0 + ty + i) * K_ + k0 + tx] = f2bf(t[tx][ty + i]);
}

// ---- qkv tail for 8-wave/16-row blocks (embed kernel only) ----------------
__device__ __forceinline__ void qkv_from_Ab8(
    const unsigned short* Ab, const unsigned short* __restrict__ wqkv,
    unsigned short* __restrict__ qb, unsigned short* __restrict__ kb,
    unsigned short* __restrict__ vtb, int r0, int w, int quad, int c16) {
  short8 af[8];
#pragma unroll
  for (int k = 0; k < 8; ++k)
    af[k] = *(const short8*)&Ab[c16 * AB_STR + k * 32 + quad * 8];
#pragma unroll
  for (int tp = 0; tp < 3; ++tp) {
    const int cb0 = (w * 6 + tp * 2) * 16 + c16;
    const int cb1 = cb0 + 16;
    const unsigned short* B0 = wqkv + (size_t)cb0 * D + quad * 8;
    const unsigned short* B1 = wqkv + (size_t)cb1 * D + quad * 8;
    floatx4 a0 = {0.f, 0.f, 0.f, 0.f}, a1 = {0.f, 0.f, 0.f, 0.f};
#pragma unroll
    for (int k = 0; k < 8; ++k) {
      a0 = MFMA(af[k], *(const short8*)(B0 + k * 32), a0);
      a1 = MFMA(af[k], *(const short8*)(B1 + k * 32), a1);
    }
#pragma unroll
    for (int e = 0; e < 4; ++e) {
      const int grow = r0 + quad * 4 + e;
#pragma unroll
      for (int half = 0; half < 2; ++half) {
        int gc = half ? cb1 : cb0;
        float v = half ? a1[e] : a0[e];
        if (gc < 256)      qb[(size_t)grow * D + gc] = f2bf(v * QSCALE);
        else if (gc < 512) kb[(size_t)grow * D + (gc - 256)] = f2bf(v);
        else               vtb[(size_t)(gc - 512) * N + grow] = f2bf(v);
      }
    }
  }
}

// ---- embed + layer-0 QKV --------------------------------------------------
__global__ __launch_bounds__(512) void k_embed_qkv(
    const int* __restrict__ nt, const float* __restrict__ emb,
    const unsigned short* __restrict__ wqkv0, float* __restrict__ x,
    unsigned short* __restrict__ qb, unsigned short* __restrict__ kb,
    unsigned short* __restrict__ vtb) {
  __shared__ __align__(16) unsigned short Ab[16 * AB_STR];
  const int tid = threadIdx.x;
  const int w = tid >> 6, lane = tid & 63, quad = lane >> 4, c16 = lane & 15;
  const int r0 = blockIdx.x * 16;
  {
    const int r = tid >> 5, cb = (tid & 31) * 8;
    const int ty = nt[r0 + r];
    float4 a = *(const float4*)&emb[(size_t)ty * D + cb];
    float4 b = *(const float4*)&emb[(size_t)ty * D + cb + 4];
    *(float4*)&x[(size_t)(r0 + r) * D + cb] = a;
    *(float4*)&x[(size_t)(r0 + r) * D + cb + 4] = b;
    Ab[r * AB_STR + cb + 0] = f2bf(a.x); Ab[r * AB_STR + cb + 1] = f2bf(a.y);
    Ab[r * AB_STR + cb + 2] = f2bf(a.z); Ab[r * AB_STR + cb + 3] = f2bf(a.w);
    Ab[r * AB_STR + cb + 4] = f2bf(b.x); Ab[r * AB_STR + cb + 5] = f2bf(b.y);
    Ab[r * AB_STR + cb + 6] = f2bf(b.z); Ab[r * AB_STR + cb + 7] = f2bf(b.w);
  }
  __syncthreads();
  qkv_from_Ab8(Ab, wqkv0, qb, kb, vtb, r0, w, quad, c16);
}

// ---- MFMA flash attention: QBLK=32, JC=8, m=0, contiguous-P ---------------
__global__ __launch_bounds__(512) void k_attn(const unsigned short* __restrict__ qb,
                                              const unsigned short* __restrict__ kb,
                                              const unsigned short* __restrict__ vt,
                                              const unsigned int* __restrict__ e8,
                                              const float* __restrict__ eb,
                                              float* __restrict__ Opart,
                                              float* __restrict__ lpart) {
  __shared__ __align__(16) unsigned short Pb[H][32 * PB_STR];
  __shared__ float ebh[H][NEDGE];
  __shared__ unsigned int e8s[32][65];
  const int tid = threadIdx.x;
  const int h = tid >> 6;
  const int lane = tid & 63;
  const int quad = lane >> 4;
  const int c16 = lane & 15;
  const int r0 = blockIdx.x * 32;
  const int jc = blockIdx.y;

  if (tid < NEDGE * H) ebh[tid % H][tid / H] = eb[tid] * LOG2E;
  for (int i = tid; i < 32 * 64; i += 512) {
    int r = i >> 6, ww = i & 63;
    e8s[r][ww] = e8[(size_t)(r0 + r) * (N / 4) + jc * 64 + ww];
  }
  __syncthreads();

  short8 aqA = *(const short8*)&qb[(size_t)(r0 + c16) * D + h * DK + quad * 8];
  short8 aqB = *(const short8*)&qb[(size_t)(r0 + 16 + c16) * D + h * DK + quad * 8];

  float lrowA[4] = {0.f, 0.f, 0.f, 0.f};
  float lrowB[4] = {0.f, 0.f, 0.f, 0.f};
  floatx4 O0A = {0.f, 0.f, 0.f, 0.f}, O1A = {0.f, 0.f, 0.f, 0.f};
  floatx4 O0B = {0.f, 0.f, 0.f, 0.f}, O1B = {0.f, 0.f, 0.f, 0.f};

  for (int g = 0; g < (N / JC) / 64; ++g) {
    const int j0 = jc * (N / JC) + g * 64;
    short8 bk[4];
#pragma unroll
    for (int t = 0; t < 4; ++t)
      bk[t] = *(const short8*)&kb[(size_t)(j0 + c16 * 4 + t) * D + h * DK + quad * 8];
    {
      unsigned int wrd[4];
#pragma unroll
      for (int e = 0; e < 4; ++e) wrd[e] = e8s[quad * 4 + e][g * 16 + c16];
      floatx4 Sc[4];
#pragma unroll
      for (int t = 0; t < 4; ++t) {
        floatx4 cbv;
#pragma unroll
        for (int e = 0; e < 4; ++e) cbv[e] = ebh[h][(wrd[e] >> (8 * t)) & 0xff];
        Sc[t] = MFMA(aqA, bk[t], cbv);
      }
      float p[4][4];
#pragma unroll
      for (int e = 0; e < 4; ++e) {
#pragma unroll
        for (int t = 0; t < 4; ++t) p[t][e] = exp2_hw(Sc[t][e]);
        lrowA[e] += (p[0][e] + p[1][e]) + (p[2][e] + p[3][e]);
      }
#pragma unroll
      for (int e = 0; e < 4; ++e) {
        uint2 u;
        u.x = cvt_pk_bf16(p[0][e], p[1][e]);
        u.y = cvt_pk_bf16(p[2][e], p[3][e]);
        *(uint2*)&Pb[h][(quad * 4 + e) * PB_STR + c16 * 4] = u;
      }
    }
    {
      unsigned int wrd[4];
#pragma unroll
      for (int e = 0; e < 4; ++e) wrd[e] = e8s[16 + quad * 4 + e][g * 16 + c16];
      floatx4 Sc[4];
#pragma unroll
      for (int t = 0; t < 4; ++t) {
        floatx4 cbv;
#pragma unroll
        for (int e = 0; e < 4; ++e) cbv[e] = ebh[h][(wrd[e] >> (8 * t)) & 0xff];
        Sc[t] = MFMA(aqB, bk[t], cbv);
      }
      float p[4][4];
#pragma unroll
      for (int e = 0; e < 4; ++e) {
#pragma unroll
        for (int t = 0; t < 4; ++t) p[t][e] = exp2_hw(Sc[t][e]);
        lrowB[e] += (p[0][e] + p[1][e]) + (p[2][e] + p[3][e]);
      }
#pragma unroll
      for (int e = 0; e < 4; ++e) {
        uint2 u;
        u.x = cvt_pk_bf16(p[0][e], p[1][e]);
        u.y = cvt_pk_bf16(p[2][e], p[3][e]);
        *(uint2*)&Pb[h][(16 + quad * 4 + e) * PB_STR + c16 * 4] = u;
      }
    }
    asm volatile("" ::: "memory");
#pragma unroll
    for (int jj = 0; jj < 2; ++jj) {
      short8 apA = *(const short8*)&Pb[h][c16 * PB_STR + jj * 32 + quad * 8];
      short8 apB = *(const short8*)&Pb[h][(16 + c16) * PB_STR + jj * 32 + quad * 8];
      short8 bv0 = *(const short8*)&vt[(size_t)(h * DK + c16) * N + j0 + jj * 32 + quad * 8];
      short8 bv1 = *(const short8*)&vt[(size_t)(h * DK + 16 + c16) * N + j0 + jj * 32 + quad * 8];
      O0A = MFMA(apA, bv0, O0A); O1A = MFMA(apA, bv1, O1A);
      O0B = MFMA(apB, bv0, O0B); O1B = MFMA(apB, bv1, O1B);
    }
    asm volatile("" ::: "memory");
  }

#pragma unroll
  for (int e = 0; e < 4; ++e) {
    float va = lrowA[e], vb = lrowB[e];
    va += __shfl_xor(va, 1); va += __shfl_xor(va, 2);
    va += __shfl_xor(va, 4); va += __shfl_xor(va, 8);
    vb += __shfl_xor(vb, 1); vb += __shfl_xor(vb, 2);
    vb += __shfl_xor(vb, 4); vb += __shfl_xor(vb, 8);
    lrowA[e] = va; lrowB[e] = vb;
  }
#pragma unroll
  for (int e = 0; e < 4; ++e) {
    int rowA = r0 + quad * 4 + e, rowB = rowA + 16;
    size_t obA = ((size_t)jc * N + rowA) * D + h * DK;
    size_t obB = ((size_t)jc * N + rowB) * D + h * DK;
    Opart[obA + c16] = O0A[e];
    Opart[obA + 16 + c16] = O1A[e];
    Opart[obB + c16] = O0B[e];
    Opart[obB + 16 + c16] = O1B[e];
    if (c16 == 0) {
      lpart[((size_t)jc * N + rowA) * H + h] = lrowA[e];
      lpart[((size_t)jc * N + rowB) * H + h] = lrowB[e];
    }
  }
}

// ---- fused: attn-combine -> out-proj GEMM -> +bo +res -> LN1 -> x, xb -----
// grid N/16 = 128 blocks x 256 thr (4 waves). Block owns 16 COMPLETE rows.
__global__ __launch_bounds__(256) void k_opln1(
    const float* __restrict__ Opart, const float* __restrict__ lpart,
    const unsigned short* __restrict__ wo, const float* __restrict__ bo,
    const float* __restrict__ g1, const float* __restrict__ be1,
    float* __restrict__ x, unsigned short* __restrict__ xb) {
  __shared__ __align__(16) unsigned short Ab[16 * AB_STR];
  __shared__ __align__(16) float Xr[16][260];
  __shared__ float linv[16][8];
  __shared__ float red1[4][16], red2[4][16], mu[16], rsg[16];
  const int tid = threadIdx.x;
  const int w = tid >> 6, lane = tid & 63, quad = lane >> 4, c16 = lane & 15;
  const int r0 = blockIdx.x * 16;

  if (tid < 128) {
    int r = tid >> 3, hh = tid & 7;
    float ls = 0.f;
#pragma unroll
    for (int c = 0; c < JC; ++c) ls += lpart[((size_t)c * N + r0 + r) * H + hh];
    linv[r][hh] = 1.f / ls;
  }
  for (int i = tid; i < 16 * 64; i += 256) {
    int r = i >> 6, c4 = (i & 63) * 4;
    *(float4*)&Xr[r][c4] = *(const float4*)&x[(size_t)(r0 + r) * D + c4];
  }
  __syncthreads();
  {
    const int r = tid >> 4, c0 = (tid & 15) * 16;
    float o[16];
#pragma unroll
    for (int j = 0; j < 16; ++j) o[j] = 0.f;
#pragma unroll
    for (int c = 0; c < JC; ++c) {
      const float* p = &Opart[((size_t)c * N + r0 + r) * D + c0];
#pragma unroll
      for (int j4 = 0; j4 < 4; ++j4) {
        float4 pv = *(const float4*)(p + j4 * 4);
        o[j4 * 4 + 0] += pv.x; o[j4 * 4 + 1] += pv.y;
        o[j4 * 4 + 2] += pv.z; o[j4 * 4 + 3] += pv.w;
      }
    }
    const float iv = linv[r][c0 >> 5];
#pragma unroll
    for (int j = 0; j < 16; j += 2)
      *(unsigned int*)&Ab[r * AB_STR + c0 + j] = cvt_pk_bf16(o[j] * iv, o[j + 1] * iv);
  }
  __syncthreads();

  short8 af[8];
#pragma unroll
  for (int k = 0; k < 8; ++k)
    af[k] = *(const short8*)&Ab[c16 * AB_STR + k * 32 + quad * 8];
  floatx4 acc[4] = {{0.f, 0.f, 0.f, 0.f}, {0.f, 0.f, 0.f, 0.f},
                    {0.f, 0.f, 0.f, 0.f}, {0.f, 0.f, 0.f, 0.f}};
#pragma unroll
  for (int ntt = 0; ntt < 4; ++ntt) {
    const int col = w * 64 + ntt * 16 + c16;
    const unsigned short* B = wo + (size_t)col * D + quad * 8;
#pragma unroll
    for (int k = 0; k < 8; ++k) acc[ntt] = MFMA(af[k], *(const short8*)(B + k * 32), acc[ntt]);
  }
  float v[4][4];
#pragma unroll
  for (int e = 0; e < 4; ++e) {
    const int row = quad * 4 + e;
    float s = 0.f, q = 0.f;
#pragma unroll
    for (int ntt = 0; ntt < 4; ++ntt) {
      const int col = w * 64 + ntt * 16 + c16;
      float vv = acc[ntt][e] + bo[col] + Xr[row][col];
      v[ntt][e] = vv;
      s += vv; q += vv * vv;
    }
    s += __shfl_xor(s, 1); s += __shfl_xor(s, 2);
    s += __shfl_xor(s, 4); s += __shfl_xor(s, 8);
    q += __shfl_xor(q, 1); q += __shfl_xor(q, 2);
    q += __shfl_xor(q, 4); q += __shfl_xor(q, 8);
    if (c16 == 0) { red1[w][row] = s; red2[w][row] = q; }
  }
  __syncthreads();
  if (tid < 16) {
    float m = red1[0][tid] + red1[1][tid] + red1[2][tid] + red1[3][tid];
    float q = red2[0][tid] + red2[1][tid] + red2[2][tid] + red2[3][tid];
    m *= (1.f / 256.f);
    q = q * (1.f / 256.f) - m * m;
    mu[tid] = m;
    rsg[tid] = rsqrtf(q + 1e-5f);
  }
  __syncthreads();
#pragma unroll
  for (int e = 0; e < 4; ++e) {
    const int row = quad * 4 + e;
#pragma unroll
    for (int ntt = 0; ntt < 4; ++ntt) {
      const int col = w * 64 + ntt * 16 + c16;
      float o = (v[ntt][e] - mu[row]) * rsg[row] * g1[col] + be1[col];
      x[(size_t)(r0 + row) * D + col] = o;
      xb[(size_t)(r0 + row) * D + col] = f2bf(o);
    }
  }
}

// ---- bf16 MFMA GEMM (FFN1 only): C = A @ Bt^T +bias +gelu -> bf16 ---------
__global__ __launch_bounds__(256) void k_mm(const unsigned short* __restrict__ A,
                                            const unsigned short* __restrict__ Bt,
                                            int Nn, int Kfull, int Klen,
                                            const float* __restrict__ bias,
                                            int gelu,
                                            float* __restrict__ outf,
                                            unsigned short* __restrict__ outb) {
  __shared__ unsigned short As[64 * 32];
  __shared__ unsigned short Bs[64 * 32];
  int tid = threadIdx.x;
  int w = tid >> 6, lane = tid & 63, quad = lane >> 4, c16 = lane & 15;
  int bm = blockIdx.y * 64, bn = blockIdx.x * 64;
  int z = blockIdx.z;
  int kBase = z * Klen;
  int srow = w * 16 + (lane >> 2);
  int schk = (lane & 3) * 8;
  const unsigned short* gA = A + (size_t)(bm + srow) * Kfull + kBase + schk;
  const unsigned short* gB = Bt + (size_t)(bn + srow) * Kfull + kBase + schk;
  unsigned short* lA = &As[w * 512 + lane * 8];
  unsigned short* lB = &Bs[w * 512 + lane * 8];

  floatx4 acc[4] = {{0.f, 0.f, 0.f, 0.f}, {0.f, 0.f, 0.f, 0.f},
                    {0.f, 0.f, 0.f, 0.f}, {0.f, 0.f, 0.f, 0.f}};
  for (int k0 = 0; k0 < Klen; k0 += 32) {
    async16(lA, gA + k0);
    async16(lB, gB + k0);
    __syncthreads();
    short8 a = *(const short8*)&As[(w * 16 + c16) * 32 + quad * 8];
#pragma unroll
    for (int ntt = 0; ntt < 4; ++ntt) {
      short8 b = *(const short8*)&Bs[(ntt * 16 + c16) * 32 + quad * 8];
      acc[ntt] = MFMA(a, b, acc[ntt]);
    }
    __syncthreads();
  }
#pragma unroll
  for (int ntt = 0; ntt < 4; ++ntt) {
#pragma unroll
    for (int e = 0; e < 4; ++e) {
      int row = bm + w * 16 + quad * 4 + e;
      int col = bn + ntt * 16 + c16;
      float v = acc[ntt][e];
      if (z == 0) v += bias[col];
      if (gelu) v = 0.5f * v * (1.0f + erff(v * 0.70710678118654752f));
      if (outf) outf[(size_t)z * N * Nn + (size_t)row * Nn + col] = v;
      if (outb) outb[(size_t)row * Nn + col] = f2bf(v);
    }
  }
}

// ---- fused: FFN2 GEMM (complete rows, K=1024) -> +b2 +res -> LN2 ----------
// grid N/16 = 128 blocks x 256 thr (4 waves); block owns 16 complete rows.
// hb row-tile staged once in LDS (no intra-k-loop barriers); w2 is shared by
// all blocks and stays L2-resident. LN2 + pool partials in epilogue.
__global__ __launch_bounds__(256) void k_ffn2ln(
    const unsigned short* __restrict__ hb, const unsigned short* __restrict__ w2,
    const float* __restrict__ b2,
    const float* __restrict__ g2, const float* __restrict__ be2,
    float* __restrict__ x, unsigned short* __restrict__ xb,
    float* __restrict__ ppool) {
  __shared__ __align__(16) unsigned short Hs[16 * HS_STR];
  __shared__ __align__(16) float Xr[16][260];
  __shared__ float red1[4][16], red2[4][16], mu[16], rsg[16];
  const int tid = threadIdx.x;
  const int w = tid >> 6, lane = tid & 63, quad = lane >> 4, c16 = lane & 15;
  const int r0 = blockIdx.x * 16;

  // stage Hs: wave covers half-row (64 lanes x 8 bf16 = 512 cols), 8 passes
  {
    const int half = w & 1, rbase = w >> 1;
#pragma unroll
    for (int pass = 0; pass < 8; ++pass) {
      const int r = pass * 2 + rbase;
      async16(&Hs[r * HS_STR + half * 512 + lane * 8],
              hb + (size_t)(r0 + r) * DFF + half * 512 + lane * 8);
    }
  }
  for (int i = tid; i < 16 * 64; i += 256) {
    int r = i >> 6, c4 = (i & 63) * 4;
    *(float4*)&Xr[r][c4] = *(const float4*)&x[(size_t)(r0 + r) * D + c4];
  }
  __syncthreads();

  floatx4 acc[4] = {{0.f, 0.f, 0.f, 0.f}, {0.f, 0.f, 0.f, 0.f},
                    {0.f, 0.f, 0.f, 0.f}, {0.f, 0.f, 0.f, 0.f}};
  for (int k = 0; k < 32; ++k) {
    short8 a = *(const short8*)&Hs[c16 * HS_STR + k * 32 + quad * 8];
#pragma unroll
    for (int ntt = 0; ntt < 4; ++ntt) {
      const int col = w * 64 + ntt * 16 + c16;
      short8 b = *(const short8*)(w2 + (size_t)col * DFF + k * 32 + quad * 8);
      acc[ntt] = MFMA(a, b, acc[ntt]);
    }
  }

  float v[4][4];
#pragma unroll
  for (int e = 0; e < 4; ++e) {
    const int row = quad * 4 + e;
    float s = 0.f, q = 0.f;
#pragma unroll
    for (int ntt = 0; ntt < 4; ++ntt) {
      const int col = w * 64 + ntt * 16 + c16;
      float vv = acc[ntt][e] + b2[col] + Xr[row][col];
      v[ntt][e] = vv;
      s += vv; q += vv * vv;
    }
    s += __shfl_xor(s, 1); s += __shfl_xor(s, 2);
    s += __shfl_xor(s, 4); s += __shfl_xor(s, 8);
    q += __shfl_xor(q, 1); q += __shfl_xor(q, 2);
    q += __shfl_xor(q, 4); q += __shfl_xor(q, 8);
    if (c16 == 0) { red1[w][row] = s; red2[w][row] = q; }
  }
  __syncthreads();
  if (tid < 16) {
    float m = red1[0][tid] + red1[1][tid] + red1[2][tid] + red1[3][tid];
    float q = red2[0][tid] + red2[1][tid] + red2[2][tid] + red2[3][tid];
    m *= (1.f / 256.f);
    q = q * (1.f / 256.f) - m * m;
    mu[tid] = m;
    rsg[tid] = rsqrtf(q + 1e-5f);
  }
  __syncthreads();
  float psum[4], pmax[4];
#pragma unroll
  for (int ntt = 0; ntt < 4; ++ntt) { psum[ntt] = 0.f; pmax[ntt] = -INFINITY; }
#pragma unroll
  for (int e = 0; e < 4; ++e) {
    const int row = quad * 4 + e;
#pragma unroll
    for (int ntt = 0; ntt < 4; ++ntt) {
      const int col = w * 64 + ntt * 16 + c16;
      float o = (v[ntt][e] - mu[row]) * rsg[row] * g2[col] + be2[col];
      x[(size_t)(r0 + row) * D + col] = o;
      xb[(size_t)(r0 + row) * D + col] = f2bf(o);
      psum[ntt] += o;
      pmax[ntt] = fmaxf(pmax[ntt], o);
    }
  }
  if (ppool) {
    // reduce across quads (lane bits 4,5) -> 16-row totals per col
#pragma unroll
    for (int ntt = 0; ntt < 4; ++ntt) {
      psum[ntt] += __shfl_xor(psum[ntt], 16);
      psum[ntt] += __shfl_xor(psum[ntt], 32);
      pmax[ntt] = fmaxf(pmax[ntt], __shfl_xor(pmax[ntt], 16));
      pmax[ntt] = fmaxf(pmax[ntt], __shfl_xor(pmax[ntt], 32));
    }
    if (quad == 0) {
      float* pp = ppool + (size_t)blockIdx.x * 512;
#pragma unroll
      for (int ntt = 0; ntt < 4; ++ntt) {
        const int col = w * 64 + ntt * 16 + c16;
        pp[col] = psum[ntt];
        pp[256 + col] = pmax[ntt];
      }
    }
  }
}

// ---- fused QKV GEMM: Nn=768; writes qb (pre-scaled), kb, vt (D,N) bf16 ----
__global__ __launch_bounds__(256) void k_mm_qkv(const unsigned short* __restrict__ A,
                                                const unsigned short* __restrict__ Bt,
                                                unsigned short* __restrict__ qb,
                                                unsigned short* __restrict__ kb,
                                                unsigned short* __restrict__ vtb) {
  const int K = D;
  __shared__ unsigned short As[64 * 32];
  __shared__ unsigned short Bs[64 * 32];
  int tid = threadIdx.x;
  int w = tid >> 6, lane = tid & 63, quad = lane >> 4, c16 = lane & 15;
  int bm = blockIdx.y * 64, bn = blockIdx.x * 64;
  int srow = w * 16 + (lane >> 2);
  int schk = (lane & 3) * 8;
  const unsigned short* gA = A + (size_t)(bm + srow) * K + schk;
  const unsigned short* gB = Bt + (size_t)(bn + srow) * K + schk;
  unsigned short* lA = &As[w * 512 + lane * 8];
  unsigned short* lB = &Bs[w * 512 + lane * 8];

  floatx4 acc[4] = {{0.f, 0.f, 0.f, 0.f}, {0.f, 0.f, 0.f, 0.f},
                    {0.f, 0.f, 0.f, 0.f}, {0.f, 0.f, 0.f, 0.f}};
  for (int k0 = 0; k0 < K; k0 += 32) {
    async16(lA, gA + k0);
    async16(lB, gB + k0);
    __syncthreads();
    short8 a = *(const short8*)&As[(w * 16 + c16) * 32 + quad * 8];
#pragma unroll
    for (int ntt = 0; ntt < 4; ++ntt) {
      short8 b = *(const short8*)&Bs[(ntt * 16 + c16) * 32 + quad * 8];
      acc[ntt] = MFMA(a, b, acc[ntt]);
    }
    __syncthreads();
  }
#pragma unroll
  for (int ntt = 0; ntt < 4; ++ntt) {
#pragma unroll
    for (int e = 0; e < 4; ++e) {
      int row = bm + w * 16 + quad * 4 + e;
      int col = bn + ntt * 16 + c16;  // q:0-255, k:256-511, v:512-767
      float v = acc[ntt][e];
      if (col < 256) v *= QSCALE;
      unsigned short bv = f2bf(v);
      if (col < 512) {
        unsigned short* dst = (col < 256) ? qb : kb;
        dst[(size_t)row * D + (col & 255)] = bv;
      } else {
        vtb[(size_t)(col - 512) * N + row] = bv;
      }
    }
  }
}

// ---- pool phase 2: reduce 128 partials + project (WrT contiguous rows) ----
__global__ __launch_bounds__(256) void k_pool2(const float* __restrict__ part,
                                               const float* __restrict__ WrT,
                                               const float* __restrict__ br,
                                               float* __restrict__ out) {
  __shared__ float pooled[2 * D];
  int d = threadIdx.x;
  float sum = 0.f, mx = -INFINITY;
  for (int b = 0; b < 128; ++b) {
    sum += part[(size_t)b * 512 + d];
    mx = fmaxf(mx, part[(size_t)b * 512 + 256 + d]);
  }
  pooled[d] = sum * (1.0f / N);
  pooled[D + d] = mx;
  __syncthreads();
  float acc = br[d];
  const float* wrow = WrT + (size_t)d * 512;
#pragma unroll 8
  for (int k2 = 0; k2 < 512; k2 += 4) {
    float4 wv = *(const float4*)(wrow + k2);
    acc += pooled[k2] * wv.x + pooled[k2 + 1] * wv.y +
           pooled[k2 + 2] * wv.z + pooled[k2 + 3] * wv.w;
  }
  out[d] = acc;
}

extern "C" void kernel_launch(void* const* d_in, const int* in_sizes, int n_in,
                              void* d_out, int out_size, void* d_ws, size_t ws_size,
                              hipStream_t stream) {
  const int* node_types = (const int*)d_in[0];
  const int* eidx = (const int*)d_in[1];
  const float* node_emb = (const float*)d_in[2];
  const float* Wq = (const float*)d_in[3];
  const float* Wk = (const float*)d_in[4];
  const float* Wv = (const float*)d_in[5];
  const float* Wo = (const float*)d_in[6];
  const float* bo = (const float*)d_in[7];
  const float* eb = (const float*)d_in[8];
  const float* W1 = (const float*)d_in[9];
  const float* b1 = (const float*)d_in[10];
  const float* W2 = (const float*)d_in[11];
  const float* b2 = (const float*)d_in[12];
  const float* g1 = (const float*)d_in[13];
  const float* be1 = (const float*)d_in[14];
  const float* g2 = (const float*)d_in[15];
  const float* be2 = (const float*)d_in[16];
  const float* Wr = (const float*)d_in[17];
  const float* br = (const float*)d_in[18];
  float* out = (float*)d_out;

  // workspace layout
  float* x = (float*)d_ws;                       // N*D fp32
  float* Opart = x + (size_t)N * D;              // JC*N*D fp32
  float* lpart = Opart + (size_t)JC * N * D;     // JC*N*H
  float* ppool = lpart + (size_t)JC * N * H;     // 128*512
  float* WrT = ppool + 128 * 512;                // 256*512 fp32
  unsigned short* xb = (unsigned short*)(WrT + 256 * 512);
  unsigned short* qb = xb + (size_t)N * D;
  unsigned short* kb = qb + (size_t)N * D;
  unsigned short* vtb = kb + (size_t)N * D;      // (D, N) head-major d
  unsigned short* hb = vtb + (size_t)N * D;      // N*DFF
  unsigned short* wqkvb = hb + (size_t)N * DFF;  // L x (768, 256)
  unsigned short* wob = wqkvb + (size_t)L * 768 * D;
  unsigned short* w1b = wob + (size_t)L * D * D;
  unsigned short* w2b = w1b + (size_t)L * DFF * D;
  unsigned int* e8 = (unsigned int*)(w2b + (size_t)L * D * DFF);  // N*N bytes

  k_setup<<<7296, 256, 0, stream>>>(eidx, e8, Wq, Wk, Wv, Wo, W1, W2, Wr,
                                    wqkvb, wob, w1b, w2b, WrT);
  k_embed_qkv<<<128, 512, 0, stream>>>(node_types, node_emb, wqkvb, x, qb, kb, vtb);

  for (int l = 0; l < L; ++l) {
    k_attn<<<dim3(N / 32, JC), 512, 0, stream>>>(qb, kb, vtb, e8,
                                                 eb + (size_t)l * NEDGE * H,
                                                 Opart, lpart);
    k_opln1<<<N / 16, 256, 0, stream>>>(Opart, lpart,
                                        wob + (size_t)l * D * D, bo + (size_t)l * D,
                                        g1 + (size_t)l * D, be1 + (size_t)l * D, x, xb);
    k_mm<<<dim3(DFF / 64, N / 64, 1), 256, 0, stream>>>(
        xb, w1b + (size_t)l * DFF * D, DFF, D, D, b1 + (size_t)l * DFF, 1,
        (float*)nullptr, hb);
    k_ffn2ln<<<N / 16, 256, 0, stream>>>(
        hb, w2b + (size_t)l * D * DFF, b2 + (size_t)l * D,
        g2 + (size_t)l * D, be2 + (size_t)l * D, x, xb,
        (l == L - 1) ? ppool : nullptr);
    if (l < L - 1) {
      k_mm_qkv<<<dim3(768 / 64, N / 64), 256, 0, stream>>>(
          xb, wqkvb + (size_t)(l + 1) * 768 * D, qb, kb, vtb);
    }
  }

  k_pool2<<<1, 256, 0, stream>>>(ppool, WrT, br, out);
}

// Round 10
// 408.838 us; speedup vs baseline: 1.9409x; 1.0192x over previous
//
#include <hip/hip_runtime.h>
#include <math.h>

#define N 2048
#define D 256
#define H 8
#define DK 32
#define L 4
#define DFF 1024
#define NEDGE 5
#define JC 8  // attention j-chunks (flash-decode split)

typedef short short8 __attribute__((ext_vector_type(8)));
typedef float floatx4 __attribute__((ext_vector_type(4)));

// Q pre-scale: 1/sqrt(DK) * log2(e)  (attention uses raw v_exp_f32 = exp2)
#define QSCALE 0.25503485657f
#define LOG2E 1.4426950408889634f

#define MFMA(a, b, c) __builtin_amdgcn_mfma_f32_16x16x32_bf16(a, b, c, 0, 0, 0)

#define AB_STR 280   // (280*2/4)%32 = 12-bank row stride -> 2-way alias (free)
#define PB_STR 72
#define HS_STR 1048  // same 12-bank residue as AB_STR

__device__ __forceinline__ unsigned short f2bf(float f) {
  unsigned int u = __float_as_uint(f);
  u += 0x7fffu + ((u >> 16) & 1u);
  return (unsigned short)(u >> 16);
}

__device__ __forceinline__ float exp2_hw(float x) {
  float r;
  asm("v_exp_f32 %0, %1" : "=v"(r) : "v"(x));
  return r;
}

__device__ __forceinline__ unsigned int cvt_pk_bf16(float lo, float hi) {
  unsigned int r;
  asm("v_cvt_pk_bf16_f32 %0, %1, %2" : "=v"(r) : "v"(lo), "v"(hi));
  return r;
}

__device__ __forceinline__ void async16(unsigned short* lds, const unsigned short* g) {
  __builtin_amdgcn_global_load_lds(
      (const __attribute__((address_space(1))) unsigned int*)g,
      (__attribute__((address_space(3))) unsigned int*)lds, 16, 0, 0);
}

// ---- setup: e8 pack + weight transposes + WrT fp32 ------------------------
__global__ __launch_bounds__(256) void k_setup(
    const int* __restrict__ eidx, unsigned int* __restrict__ e8,
    const float* __restrict__ Wq, const float* __restrict__ Wk,
    const float* __restrict__ Wv, const float* __restrict__ Wo,
    const float* __restrict__ W1, const float* __restrict__ W2,
    const float* __restrict__ Wr,
    unsigned short* __restrict__ wqkvb, unsigned short* __restrict__ wob,
    unsigned short* __restrict__ w1b, unsigned short* __restrict__ w2b,
    float* __restrict__ WrT) {
  __shared__ float t[32][33];
  const int blk = blockIdx.x;
  const int tid = threadIdx.x;
  if (blk < 4096) {
    int i = blk * 256 + tid;  // word i = cols 4i..4i+3 of row i/512
    int4 v = ((const int4*)eidx)[i];
    e8[i] = (unsigned int)(v.x & 0xff) | ((unsigned int)(v.y & 0xff) << 8) |
            ((unsigned int)(v.z & 0xff) << 16) | ((unsigned int)(v.w & 0xff) << 24);
    return;
  }
  const int tx = tid & 31, ty = tid >> 5;
  if (blk >= 7168) {  // Wr (512,256) fp32 -> WrT (256,512) fp32
    int b5 = blk - 7168, bx = b5 & 7, by = b5 >> 3;
#pragma unroll
    for (int i = 0; i < 32; i += 8)
      t[ty + i][tx] = Wr[(size_t)(by * 32 + ty + i) * D + bx * 32 + tx];
    __syncthreads();
#pragma unroll
    for (int i = 0; i < 32; i += 8)
      WrT[(size_t)(bx * 32 + ty + i) * 512 + by * 32 + tx] = t[tx][ty + i];
    return;
  }
  const float* s;
  unsigned short* d;
  int rowOff, K_, N_, bx, by;
  if (blk < 5120) {
    int b2 = blk - 4096, z = b2 >> 6, rem = b2 & 63;
    int which = z >> 2, l = z & 3;
    s = (which == 0 ? Wq : which == 1 ? Wk : which == 2 ? Wv : Wo) + (size_t)l * D * D;
    if (which < 3) { d = wqkvb + (size_t)l * 768 * D; rowOff = which * 256; }
    else           { d = wob + (size_t)l * D * D;     rowOff = 0; }
    K_ = D; N_ = D; bx = rem & 7; by = rem >> 3;
  } else if (blk < 6144) {
    int b3 = blk - 5120, l = b3 >> 8, rem = b3 & 255;
    s = W1 + (size_t)l * D * DFF; d = w1b + (size_t)l * DFF * D; rowOff = 0;
    K_ = D; N_ = DFF; bx = rem & 31; by = rem >> 5;
  } else {
    int b4 = blk - 6144, l = b4 >> 8, rem = b4 & 255;
    s = W2 + (size_t)l * DFF * D; d = w2b + (size_t)l * D * DFF; rowOff = 0;
    K_ = DFF; N_ = D; bx = rem & 7; by = rem >> 3;
  }
  int n0 = bx * 32, k0 = by * 32;
#pragma unroll
  for (int i = 0; i < 32; i += 8) t[ty + i][tx] = s[(size_t)(k0 + ty + i) * N_ + n0 + tx];
  __syncthreads();
#pragma unroll
  for (int i = 0; i < 32; i += 8)
    d[(size_t)(rowOff + n0 + ty + i) * K_ + k0 + tx] = f2bf(t[tx][ty + i]);
}

// ---- qkv tail for 8-wave/16-row blocks (embed kernel only) ----------------
__device__ __forceinline__ void qkv_from_Ab8(
    const unsigned short* Ab, const unsigned short* __restrict__ wqkv,
    unsigned short* __restrict__ qb, unsigned short* __restrict__ kb,
    unsigned short* __restrict__ vtb, int r0, int w, int quad, int c16) {
  short8 af[8];
#pragma unroll
  for (int k = 0; k < 8; ++k)
    af[k] = *(const short8*)&Ab[c16 * AB_STR + k * 32 + quad * 8];
#pragma unroll
  for (int tp = 0; tp < 3; ++tp) {
    const int cb0 = (w * 6 + tp * 2) * 16 + c16;
    const int cb1 = cb0 + 16;
    const unsigned short* B0 = wqkv + (size_t)cb0 * D + quad * 8;
    const unsigned short* B1 = wqkv + (size_t)cb1 * D + quad * 8;
    floatx4 a0 = {0.f, 0.f, 0.f, 0.f}, a1 = {0.f, 0.f, 0.f, 0.f};
#pragma unroll
    for (int k = 0; k < 8; ++k) {
      a0 = MFMA(af[k], *(const short8*)(B0 + k * 32), a0);
      a1 = MFMA(af[k], *(const short8*)(B1 + k * 32), a1);
    }
#pragma unroll
    for (int e = 0; e < 4; ++e) {
      const int grow = r0 + quad * 4 + e;
#pragma unroll
      for (int half = 0; half < 2; ++half) {
        int gc = half ? cb1 : cb0;
        float v = half ? a1[e] : a0[e];
        if (gc < 256)      qb[(size_t)grow * D + gc] = f2bf(v * QSCALE);
        else if (gc < 512) kb[(size_t)grow * D + (gc - 256)] = f2bf(v);
        else               vtb[(size_t)(gc - 512) * N + grow] = f2bf(v);
      }
    }
  }
}

// ---- embed + layer-0 QKV --------------------------------------------------
__global__ __launch_bounds__(512) void k_embed_qkv(
    const int* __restrict__ nt, const float* __restrict__ emb,
    const unsigned short* __restrict__ wqkv0, float* __restrict__ x,
    unsigned short* __restrict__ qb, unsigned short* __restrict__ kb,
    unsigned short* __restrict__ vtb) {
  __shared__ __align__(16) unsigned short Ab[16 * AB_STR];
  const int tid = threadIdx.x;
  const int w = tid >> 6, lane = tid & 63, quad = lane >> 4, c16 = lane & 15;
  const int r0 = blockIdx.x * 16;
  {
    const int r = tid >> 5, cb = (tid & 31) * 8;
    const int ty = nt[r0 + r];
    float4 a = *(const float4*)&emb[(size_t)ty * D + cb];
    float4 b = *(const float4*)&emb[(size_t)ty * D + cb + 4];
    *(float4*)&x[(size_t)(r0 + r) * D + cb] = a;
    *(float4*)&x[(size_t)(r0 + r) * D + cb + 4] = b;
    Ab[r * AB_STR + cb + 0] = f2bf(a.x); Ab[r * AB_STR + cb + 1] = f2bf(a.y);
    Ab[r * AB_STR + cb + 2] = f2bf(a.z); Ab[r * AB_STR + cb + 3] = f2bf(a.w);
    Ab[r * AB_STR + cb + 4] = f2bf(b.x); Ab[r * AB_STR + cb + 5] = f2bf(b.y);
    Ab[r * AB_STR + cb + 6] = f2bf(b.z); Ab[r * AB_STR + cb + 7] = f2bf(b.w);
  }
  __syncthreads();
  qkv_from_Ab8(Ab, wqkv0, qb, kb, vtb, r0, w, quad, c16);
}

// ---- MFMA flash attention: QBLK=32, JC=8, m=0, contiguous-P ---------------
__global__ __launch_bounds__(512) void k_attn(const unsigned short* __restrict__ qb,
                                              const unsigned short* __restrict__ kb,
                                              const unsigned short* __restrict__ vt,
                                              const unsigned int* __restrict__ e8,
                                              const float* __restrict__ eb,
                                              float* __restrict__ Opart,
                                              float* __restrict__ lpart) {
  __shared__ __align__(16) unsigned short Pb[H][32 * PB_STR];
  __shared__ float ebh[H][NEDGE];
  __shared__ unsigned int e8s[32][65];
  const int tid = threadIdx.x;
  const int h = tid >> 6;
  const int lane = tid & 63;
  const int quad = lane >> 4;
  const int c16 = lane & 15;
  const int r0 = blockIdx.x * 32;
  const int jc = blockIdx.y;

  if (tid < NEDGE * H) ebh[tid % H][tid / H] = eb[tid] * LOG2E;
  for (int i = tid; i < 32 * 64; i += 512) {
    int r = i >> 6, ww = i & 63;
    e8s[r][ww] = e8[(size_t)(r0 + r) * (N / 4) + jc * 64 + ww];
  }
  __syncthreads();

  short8 aqA = *(const short8*)&qb[(size_t)(r0 + c16) * D + h * DK + quad * 8];
  short8 aqB = *(const short8*)&qb[(size_t)(r0 + 16 + c16) * D + h * DK + quad * 8];

  float lrowA[4] = {0.f, 0.f, 0.f, 0.f};
  float lrowB[4] = {0.f, 0.f, 0.f, 0.f};
  floatx4 O0A = {0.f, 0.f, 0.f, 0.f}, O1A = {0.f, 0.f, 0.f, 0.f};
  floatx4 O0B = {0.f, 0.f, 0.f, 0.f}, O1B = {0.f, 0.f, 0.f, 0.f};

  for (int g = 0; g < (N / JC) / 64; ++g) {
    const int j0 = jc * (N / JC) + g * 64;
    short8 bk[4];
#pragma unroll
    for (int t = 0; t < 4; ++t)
      bk[t] = *(const short8*)&kb[(size_t)(j0 + c16 * 4 + t) * D + h * DK + quad * 8];
    {
      unsigned int wrd[4];
#pragma unroll
      for (int e = 0; e < 4; ++e) wrd[e] = e8s[quad * 4 + e][g * 16 + c16];
      floatx4 Sc[4];
#pragma unroll
      for (int t = 0; t < 4; ++t) {
        floatx4 cbv;
#pragma unroll
        for (int e = 0; e < 4; ++e) cbv[e] = ebh[h][(wrd[e] >> (8 * t)) & 0xff];
        Sc[t] = MFMA(aqA, bk[t], cbv);
      }
      float p[4][4];
#pragma unroll
      for (int e = 0; e < 4; ++e) {
#pragma unroll
        for (int t = 0; t < 4; ++t) p[t][e] = exp2_hw(Sc[t][e]);
        lrowA[e] += (p[0][e] + p[1][e]) + (p[2][e] + p[3][e]);
      }
#pragma unroll
      for (int e = 0; e < 4; ++e) {
        uint2 u;
        u.x = cvt_pk_bf16(p[0][e], p[1][e]);
        u.y = cvt_pk_bf16(p[2][e], p[3][e]);
        *(uint2*)&Pb[h][(quad * 4 + e) * PB_STR + c16 * 4] = u;
      }
    }
    {
      unsigned int wrd[4];
#pragma unroll
      for (int e = 0; e < 4; ++e) wrd[e] = e8s[16 + quad * 4 + e][g * 16 + c16];
      floatx4 Sc[4];
#pragma unroll
      for (int t = 0; t < 4; ++t) {
        floatx4 cbv;
#pragma unroll
        for (int e = 0; e < 4; ++e) cbv[e] = ebh[h][(wrd[e] >> (8 * t)) & 0xff];
        Sc[t] = MFMA(aqB, bk[t], cbv);
      }
      float p[4][4];
#pragma unroll
      for (int e = 0; e < 4; ++e) {
#pragma unroll
        for (int t = 0; t < 4; ++t) p[t][e] = exp2_hw(Sc[t][e]);
        lrowB[e] += (p[0][e] + p[1][e]) + (p[2][e] + p[3][e]);
      }
#pragma unroll
      for (int e = 0; e < 4; ++e) {
        uint2 u;
        u.x = cvt_pk_bf16(p[0][e], p[1][e]);
        u.y = cvt_pk_bf16(p[2][e], p[3][e]);
        *(uint2*)&Pb[h][(16 + quad * 4 + e) * PB_STR + c16 * 4] = u;
      }
    }
    asm volatile("" ::: "memory");
#pragma unroll
    for (int jj = 0; jj < 2; ++jj) {
      short8 apA = *(const short8*)&Pb[h][c16 * PB_STR + jj * 32 + quad * 8];
      short8 apB = *(const short8*)&Pb[h][(16 + c16) * PB_STR + jj * 32 + quad * 8];
      short8 bv0 = *(const short8*)&vt[(size_t)(h * DK + c16) * N + j0 + jj * 32 + quad * 8];
      short8 bv1 = *(const short8*)&vt[(size_t)(h * DK + 16 + c16) * N + j0 + jj * 32 + quad * 8];
      O0A = MFMA(apA, bv0, O0A); O1A = MFMA(apA, bv1, O1A);
      O0B = MFMA(apB, bv0, O0B); O1B = MFMA(apB, bv1, O1B);
    }
    asm volatile("" ::: "memory");
  }

#pragma unroll
  for (int e = 0; e < 4; ++e) {
    float va = lrowA[e], vb = lrowB[e];
    va += __shfl_xor(va, 1); va += __shfl_xor(va, 2);
    va += __shfl_xor(va, 4); va += __shfl_xor(va, 8);
    vb += __shfl_xor(vb, 1); vb += __shfl_xor(vb, 2);
    vb += __shfl_xor(vb, 4); vb += __shfl_xor(vb, 8);
    lrowA[e] = va; lrowB[e] = vb;
  }
#pragma unroll
  for (int e = 0; e < 4; ++e) {
    int rowA = r0 + quad * 4 + e, rowB = rowA + 16;
    size_t obA = ((size_t)jc * N + rowA) * D + h * DK;
    size_t obB = ((size_t)jc * N + rowB) * D + h * DK;
    Opart[obA + c16] = O0A[e];
    Opart[obA + 16 + c16] = O1A[e];
    Opart[obB + c16] = O0B[e];
    Opart[obB + 16 + c16] = O1B[e];
    if (c16 == 0) {
      lpart[((size_t)jc * N + rowA) * H + h] = lrowA[e];
      lpart[((size_t)jc * N + rowB) * H + h] = lrowB[e];
    }
  }
}

// ---- fused: attn-combine -> out-proj GEMM -> +bo +res -> LN1 -> x, xb -----
// grid N/16 = 128 blocks x 512 thr (8 waves). Block owns 16 COMPLETE rows;
// wave w covers cols 32w..32w+31 (2 n-tiles) -> 2 waves/SIMD latency hiding.
__global__ __launch_bounds__(512) void k_opln1(
    const float* __restrict__ Opart, const float* __restrict__ lpart,
    const unsigned short* __restrict__ wo, const float* __restrict__ bo,
    const float* __restrict__ g1, const float* __restrict__ be1,
    float* __restrict__ x, unsigned short* __restrict__ xb) {
  __shared__ __align__(16) unsigned short Ab[16 * AB_STR];
  __shared__ __align__(16) float Xr[16][260];
  __shared__ float linv[16][8];
  __shared__ float red1[8][16], red2[8][16], mu[16], rsg[16];
  const int tid = threadIdx.x;
  const int w = tid >> 6, lane = tid & 63, quad = lane >> 4, c16 = lane & 15;
  const int r0 = blockIdx.x * 16;

  if (tid < 128) {
    int r = tid >> 3, hh = tid & 7;
    float ls = 0.f;
#pragma unroll
    for (int c = 0; c < JC; ++c) ls += lpart[((size_t)c * N + r0 + r) * H + hh];
    linv[r][hh] = 1.f / ls;
  }
  for (int i = tid; i < 16 * 64; i += 512) {
    int r = i >> 6, c4 = (i & 63) * 4;
    *(float4*)&Xr[r][c4] = *(const float4*)&x[(size_t)(r0 + r) * D + c4];
  }
  __syncthreads();
  // combine -> Ab bf16 (thread: 8 cols of one row; head const per 8-chunk)
  {
    const int r = tid >> 5, c0 = (tid & 31) * 8;
    float o[8];
#pragma unroll
    for (int j = 0; j < 8; ++j) o[j] = 0.f;
#pragma unroll
    for (int c = 0; c < JC; ++c) {
      const float* p = &Opart[((size_t)c * N + r0 + r) * D + c0];
      float4 p0 = *(const float4*)p;
      float4 p1 = *(const float4*)(p + 4);
      o[0] += p0.x; o[1] += p0.y; o[2] += p0.z; o[3] += p0.w;
      o[4] += p1.x; o[5] += p1.y; o[6] += p1.z; o[7] += p1.w;
    }
    const float iv = linv[r][c0 >> 5];
#pragma unroll
    for (int j = 0; j < 8; j += 2)
      *(unsigned int*)&Ab[r * AB_STR + c0 + j] = cvt_pk_bf16(o[j] * iv, o[j + 1] * iv);
  }
  __syncthreads();

  short8 af[8];
#pragma unroll
  for (int k = 0; k < 8; ++k)
    af[k] = *(const short8*)&Ab[c16 * AB_STR + k * 32 + quad * 8];
  floatx4 acc[2] = {{0.f, 0.f, 0.f, 0.f}, {0.f, 0.f, 0.f, 0.f}};
#pragma unroll
  for (int ntt = 0; ntt < 2; ++ntt) {
    const int col = w * 32 + ntt * 16 + c16;
    const unsigned short* B = wo + (size_t)col * D + quad * 8;
#pragma unroll
    for (int k = 0; k < 8; ++k) acc[ntt] = MFMA(af[k], *(const short8*)(B + k * 32), acc[ntt]);
  }
  float v[2][4];
#pragma unroll
  for (int e = 0; e < 4; ++e) {
    const int row = quad * 4 + e;
    float s = 0.f, q = 0.f;
#pragma unroll
    for (int ntt = 0; ntt < 2; ++ntt) {
      const int col = w * 32 + ntt * 16 + c16;
      float vv = acc[ntt][e] + bo[col] + Xr[row][col];
      v[ntt][e] = vv;
      s += vv; q += vv * vv;
    }
    s += __shfl_xor(s, 1); s += __shfl_xor(s, 2);
    s += __shfl_xor(s, 4); s += __shfl_xor(s, 8);
    q += __shfl_xor(q, 1); q += __shfl_xor(q, 2);
    q += __shfl_xor(q, 4); q += __shfl_xor(q, 8);
    if (c16 == 0) { red1[w][row] = s; red2[w][row] = q; }
  }
  __syncthreads();
  if (tid < 16) {
    float m = 0.f, q = 0.f;
#pragma unroll
    for (int ww = 0; ww < 8; ++ww) { m += red1[ww][tid]; q += red2[ww][tid]; }
    m *= (1.f / 256.f);
    q = q * (1.f / 256.f) - m * m;
    mu[tid] = m;
    rsg[tid] = rsqrtf(q + 1e-5f);
  }
  __syncthreads();
#pragma unroll
  for (int e = 0; e < 4; ++e) {
    const int row = quad * 4 + e;
#pragma unroll
    for (int ntt = 0; ntt < 2; ++ntt) {
      const int col = w * 32 + ntt * 16 + c16;
      float o = (v[ntt][e] - mu[row]) * rsg[row] * g1[col] + be1[col];
      x[(size_t)(r0 + row) * D + col] = o;
      xb[(size_t)(r0 + row) * D + col] = f2bf(o);
    }
  }
}

// ---- bf16 MFMA GEMM (FFN1 only): C = A @ Bt^T +bias +gelu -> bf16 ---------
__global__ __launch_bounds__(256) void k_mm(const unsigned short* __restrict__ A,
                                            const unsigned short* __restrict__ Bt,
                                            int Nn, int Kfull, int Klen,
                                            const float* __restrict__ bias,
                                            int gelu,
                                            float* __restrict__ outf,
                                            unsigned short* __restrict__ outb) {
  __shared__ unsigned short As[64 * 32];
  __shared__ unsigned short Bs[64 * 32];
  int tid = threadIdx.x;
  int w = tid >> 6, lane = tid & 63, quad = lane >> 4, c16 = lane & 15;
  int bm = blockIdx.y * 64, bn = blockIdx.x * 64;
  int z = blockIdx.z;
  int kBase = z * Klen;
  int srow = w * 16 + (lane >> 2);
  int schk = (lane & 3) * 8;
  const unsigned short* gA = A + (size_t)(bm + srow) * Kfull + kBase + schk;
  const unsigned short* gB = Bt + (size_t)(bn + srow) * Kfull + kBase + schk;
  unsigned short* lA = &As[w * 512 + lane * 8];
  unsigned short* lB = &Bs[w * 512 + lane * 8];

  floatx4 acc[4] = {{0.f, 0.f, 0.f, 0.f}, {0.f, 0.f, 0.f, 0.f},
                    {0.f, 0.f, 0.f, 0.f}, {0.f, 0.f, 0.f, 0.f}};
  for (int k0 = 0; k0 < Klen; k0 += 32) {
    async16(lA, gA + k0);
    async16(lB, gB + k0);
    __syncthreads();
    short8 a = *(const short8*)&As[(w * 16 + c16) * 32 + quad * 8];
#pragma unroll
    for (int ntt = 0; ntt < 4; ++ntt) {
      short8 b = *(const short8*)&Bs[(ntt * 16 + c16) * 32 + quad * 8];
      acc[ntt] = MFMA(a, b, acc[ntt]);
    }
    __syncthreads();
  }
#pragma unroll
  for (int ntt = 0; ntt < 4; ++ntt) {
#pragma unroll
    for (int e = 0; e < 4; ++e) {
      int row = bm + w * 16 + quad * 4 + e;
      int col = bn + ntt * 16 + c16;
      float v = acc[ntt][e];
      if (z == 0) v += bias[col];
      if (gelu) v = 0.5f * v * (1.0f + erff(v * 0.70710678118654752f));
      if (outf) outf[(size_t)z * N * Nn + (size_t)row * Nn + col] = v;
      if (outb) outb[(size_t)row * Nn + col] = f2bf(v);
    }
  }
}

// ---- fused: FFN2 GEMM (complete rows, K=1024) -> +b2 +res -> LN2 ----------
// grid N/16 = 128 blocks x 512 thr (8 waves); wave w covers cols 32w..32w+31
// (2 n-tiles x 32 k-steps = 64 MFMA/wave) -> 2 waves/SIMD latency hiding.
__global__ __launch_bounds__(512) void k_ffn2ln(
    const unsigned short* __restrict__ hb, const unsigned short* __restrict__ w2,
    const float* __restrict__ b2,
    const float* __restrict__ g2, const float* __restrict__ be2,
    float* __restrict__ x, unsigned short* __restrict__ xb,
    float* __restrict__ ppool) {
  __shared__ __align__(16) unsigned short Hs[16 * HS_STR];
  __shared__ __align__(16) float Xr[16][260];
  __shared__ float red1[8][16], red2[8][16], mu[16], rsg[16];
  const int tid = threadIdx.x;
  const int w = tid >> 6, lane = tid & 63, quad = lane >> 4, c16 = lane & 15;
  const int r0 = blockIdx.x * 16;

  // stage Hs: 16 rows x 1024 bf16 = 2048 chunks of 8; 512 thr x 4 passes.
  // Within a wave: r fixed, chunks contiguous -> valid global_load_lds dst.
  {
#pragma unroll
    for (int pass = 0; pass < 4; ++pass) {
      const int idx = pass * 512 + tid;     // (r, chunk): r = idx>>7, c = idx&127
      const int r = idx >> 7, c = idx & 127;
      async16(&Hs[r * HS_STR + c * 8], hb + (size_t)(r0 + r) * DFF + c * 8);
    }
  }
  for (int i = tid; i < 16 * 64; i += 512) {
    int r = i >> 6, c4 = (i & 63) * 4;
    *(float4*)&Xr[r][c4] = *(const float4*)&x[(size_t)(r0 + r) * D + c4];
  }
  __syncthreads();

  floatx4 acc[2] = {{0.f, 0.f, 0.f, 0.f}, {0.f, 0.f, 0.f, 0.f}};
  const int col0 = w * 32 + c16, col1 = w * 32 + 16 + c16;
  {
    const unsigned short* B0 = w2 + (size_t)col0 * DFF + quad * 8;
    const unsigned short* B1 = w2 + (size_t)col1 * DFF + quad * 8;
    for (int k = 0; k < 32; ++k) {
      short8 a = *(const short8*)&Hs[c16 * HS_STR + k * 32 + quad * 8];
      acc[0] = MFMA(a, *(const short8*)(B0 + k * 32), acc[0]);
      acc[1] = MFMA(a, *(const short8*)(B1 + k * 32), acc[1]);
    }
  }

  float v[2][4];
#pragma unroll
  for (int e = 0; e < 4; ++e) {
    const int row = quad * 4 + e;
    float s = 0.f, q = 0.f;
#pragma unroll
    for (int ntt = 0; ntt < 2; ++ntt) {
      const int col = w * 32 + ntt * 16 + c16;
      float vv = acc[ntt][e] + b2[col] + Xr[row][col];
      v[ntt][e] = vv;
      s += vv; q += vv * vv;
    }
    s += __shfl_xor(s, 1); s += __shfl_xor(s, 2);
    s += __shfl_xor(s, 4); s += __shfl_xor(s, 8);
    q += __shfl_xor(q, 1); q += __shfl_xor(q, 2);
    q += __shfl_xor(q, 4); q += __shfl_xor(q, 8);
    if (c16 == 0) { red1[w][row] = s; red2[w][row] = q; }
  }
  __syncthreads();
  if (tid < 16) {
    float m = 0.f, q = 0.f;
#pragma unroll
    for (int ww = 0; ww < 8; ++ww) { m += red1[ww][tid]; q += red2[ww][tid]; }
    m *= (1.f / 256.f);
    q = q * (1.f / 256.f) - m * m;
    mu[tid] = m;
    rsg[tid] = rsqrtf(q + 1e-5f);
  }
  __syncthreads();
  float psum[2], pmax[2];
#pragma unroll
  for (int ntt = 0; ntt < 2; ++ntt) { psum[ntt] = 0.f; pmax[ntt] = -INFINITY; }
#pragma unroll
  for (int e = 0; e < 4; ++e) {
    const int row = quad * 4 + e;
#pragma unroll
    for (int ntt = 0; ntt < 2; ++ntt) {
      const int col = w * 32 + ntt * 16 + c16;
      float o = (v[ntt][e] - mu[row]) * rsg[row] * g2[col] + be2[col];
      x[(size_t)(r0 + row) * D + col] = o;
      xb[(size_t)(r0 + row) * D + col] = f2bf(o);
      psum[ntt] += o;
      pmax[ntt] = fmaxf(pmax[ntt], o);
    }
  }
  if (ppool) {
#pragma unroll
    for (int ntt = 0; ntt < 2; ++ntt) {
      psum[ntt] += __shfl_xor(psum[ntt], 16);
      psum[ntt] += __shfl_xor(psum[ntt], 32);
      pmax[ntt] = fmaxf(pmax[ntt], __shfl_xor(pmax[ntt], 16));
      pmax[ntt] = fmaxf(pmax[ntt], __shfl_xor(pmax[ntt], 32));
    }
    if (quad == 0) {
      float* pp = ppool + (size_t)blockIdx.x * 512;
#pragma unroll
      for (int ntt = 0; ntt < 2; ++ntt) {
        const int col = w * 32 + ntt * 16 + c16;
        pp[col] = psum[ntt];
        pp[256 + col] = pmax[ntt];
      }
    }
  }
}

// ---- fused QKV GEMM: Nn=768; writes qb (pre-scaled), kb, vt (D,N) bf16 ----
__global__ __launch_bounds__(256) void k_mm_qkv(const unsigned short* __restrict__ A,
                                                const unsigned short* __restrict__ Bt,
                                                unsigned short* __restrict__ qb,
                                                unsigned short* __restrict__ kb,
                                                unsigned short* __restrict__ vtb) {
  const int K = D;
  __shared__ unsigned short As[64 * 32];
  __shared__ unsigned short Bs[64 * 32];
  int tid = threadIdx.x;
  int w = tid >> 6, lane = tid & 63, quad = lane >> 4, c16 = lane & 15;
  int bm = blockIdx.y * 64, bn = blockIdx.x * 64;
  int srow = w * 16 + (lane >> 2);
  int schk = (lane & 3) * 8;
  const unsigned short* gA = A + (size_t)(bm + srow) * K + schk;
  const unsigned short* gB = Bt + (size_t)(bn + srow) * K + schk;
  unsigned short* lA = &As[w * 512 + lane * 8];
  unsigned short* lB = &Bs[w * 512 + lane * 8];

  floatx4 acc[4] = {{0.f, 0.f, 0.f, 0.f}, {0.f, 0.f, 0.f, 0.f},
                    {0.f, 0.f, 0.f, 0.f}, {0.f, 0.f, 0.f, 0.f}};
  for (int k0 = 0; k0 < K; k0 += 32) {
    async16(lA, gA + k0);
    async16(lB, gB + k0);
    __syncthreads();
    short8 a = *(const short8*)&As[(w * 16 + c16) * 32 + quad * 8];
#pragma unroll
    for (int ntt = 0; ntt < 4; ++ntt) {
      short8 b = *(const short8*)&Bs[(ntt * 16 + c16) * 32 + quad * 8];
      acc[ntt] = MFMA(a, b, acc[ntt]);
    }
    __syncthreads();
  }
#pragma unroll
  for (int ntt = 0; ntt < 4; ++ntt) {
#pragma unroll
    for (int e = 0; e < 4; ++e) {
      int row = bm + w * 16 + quad * 4 + e;
      int col = bn + ntt * 16 + c16;  // q:0-255, k:256-511, v:512-767
      float v = acc[ntt][e];
      if (col < 256) v *= QSCALE;
      unsigned short bv = f2bf(v);
      if (col < 512) {
        unsigned short* dst = (col < 256) ? qb : kb;
        dst[(size_t)row * D + (col & 255)] = bv;
      } else {
        vtb[(size_t)(col - 512) * N + row] = bv;
      }
    }
  }
}

// ---- pool phase 2: reduce 128 partials + project (WrT contiguous rows) ----
__global__ __launch_bounds__(256) void k_pool2(const float* __restrict__ part,
                                               const float* __restrict__ WrT,
                                               const float* __restrict__ br,
                                               float* __restrict__ out) {
  __shared__ float pooled[2 * D];
  int d = threadIdx.x;
  float sum = 0.f, mx = -INFINITY;
  for (int b = 0; b < 128; ++b) {
    sum += part[(size_t)b * 512 + d];
    mx = fmaxf(mx, part[(size_t)b * 512 + 256 + d]);
  }
  pooled[d] = sum * (1.0f / N);
  pooled[D + d] = mx;
  __syncthreads();
  float acc = br[d];
  const float* wrow = WrT + (size_t)d * 512;
#pragma unroll 8
  for (int k2 = 0; k2 < 512; k2 += 4) {
    float4 wv = *(const float4*)(wrow + k2);
    acc += pooled[k2] * wv.x + pooled[k2 + 1] * wv.y +
           pooled[k2 + 2] * wv.z + pooled[k2 + 3] * wv.w;
  }
  out[d] = acc;
}

extern "C" void kernel_launch(void* const* d_in, const int* in_sizes, int n_in,
                              void* d_out, int out_size, void* d_ws, size_t ws_size,
                              hipStream_t stream) {
  const int* node_types = (const int*)d_in[0];
  const int* eidx = (const int*)d_in[1];
  const float* node_emb = (const float*)d_in[2];
  const float* Wq = (const float*)d_in[3];
  const float* Wk = (const float*)d_in[4];
  const float* Wv = (const float*)d_in[5];
  const float* Wo = (const float*)d_in[6];
  const float* bo = (const float*)d_in[7];
  const float* eb = (const float*)d_in[8];
  const float* W1 = (const float*)d_in[9];
  const float* b1 = (const float*)d_in[10];
  const float* W2 = (const float*)d_in[11];
  const float* b2 = (const float*)d_in[12];
  const float* g1 = (const float*)d_in[13];
  const float* be1 = (const float*)d_in[14];
  const float* g2 = (const float*)d_in[15];
  const float* be2 = (const float*)d_in[16];
  const float* Wr = (const float*)d_in[17];
  const float* br = (const float*)d_in[18];
  float* out = (float*)d_out;

  // workspace layout
  float* x = (float*)d_ws;                       // N*D fp32
  float* Opart = x + (size_t)N * D;              // JC*N*D fp32
  float* lpart = Opart + (size_t)JC * N * D;     // JC*N*H
  float* ppool = lpart + (size_t)JC * N * H;     // 128*512
  float* WrT = ppool + 128 * 512;                // 256*512 fp32
  unsigned short* xb = (unsigned short*)(WrT + 256 * 512);
  unsigned short* qb = xb + (size_t)N * D;
  unsigned short* kb = qb + (size_t)N * D;
  unsigned short* vtb = kb + (size_t)N * D;      // (D, N) head-major d
  unsigned short* hb = vtb + (size_t)N * D;      // N*DFF
  unsigned short* wqkvb = hb + (size_t)N * DFF;  // L x (768, 256)
  unsigned short* wob = wqkvb + (size_t)L * 768 * D;
  unsigned short* w1b = wob + (size_t)L * D * D;
  unsigned short* w2b = w1b + (size_t)L * DFF * D;
  unsigned int* e8 = (unsigned int*)(w2b + (size_t)L * D * DFF);  // N*N bytes

  k_setup<<<7296, 256, 0, stream>>>(eidx, e8, Wq, Wk, Wv, Wo, W1, W2, Wr,
                                    wqkvb, wob, w1b, w2b, WrT);
  k_embed_qkv<<<128, 512, 0, stream>>>(node_types, node_emb, wqkvb, x, qb, kb, vtb);

  for (int l = 0; l < L; ++l) {
    k_attn<<<dim3(N / 32, JC), 512, 0, stream>>>(qb, kb, vtb, e8,
                                                 eb + (size_t)l * NEDGE * H,
                                                 Opart, lpart);
    k_opln1<<<N / 16, 512, 0, stream>>>(Opart, lpart,
                                        wob + (size_t)l * D * D, bo + (size_t)l * D,
                                        g1 + (size_t)l * D, be1 + (size_t)l * D, x, xb);
    k_mm<<<dim3(DFF / 64, N / 64, 1), 256, 0, stream>>>(
        xb, w1b + (size_t)l * DFF * D, DFF, D, D, b1 + (size_t)l * DFF, 1,
        (float*)nullptr, hb);
    k_ffn2ln<<<N / 16, 512, 0, stream>>>(
        hb, w2b + (size_t)l * D * DFF, b2 + (size_t)l * D,
        g2 + (size_t)l * D, be2 + (size_t)l * D, x, xb,
        (l == L - 1) ? ppool : nullptr);
    if (l < L - 1) {
      k_mm_qkv<<<dim3(768 / 64, N / 64), 256, 0, stream>>>(
          xb, wqkvb + (size_t)(l + 1) * 768 * D, qb, kb, vtb);
    }
  }

  k_pool2<<<1, 256, 0, stream>>>(ppool, WrT, br, out);
}